// Round 5
// baseline (634.225 us; speedup 1.0000x reference)
//
#include <hip/hip_runtime.h>

constexpr float LN_EPS = 1e-5f;

typedef __bf16 bf16x8 __attribute__((ext_vector_type(8)));
typedef float f32x4 __attribute__((ext_vector_type(4)));

__device__ __forceinline__ unsigned short f2bf(float f) {
  unsigned int u = __float_as_uint(f);
  u = (u + 0x7fffu + ((u >> 16) & 1u)) >> 16;  // RNE
  return (unsigned short)u;
}
__device__ __forceinline__ float bflo(unsigned int p) { return __uint_as_float(p << 16); }
__device__ __forceinline__ float bfhi(unsigned int p) { return __uint_as_float(p & 0xffff0000u); }

// ==================== CSR build: 8-way privatized histograms ==============
// copy index c = (i>>8)&7 == blockIdx&7 for a 2048x256 grid-stride loop
// (blocks round-robin XCDs, so copy c stays in XCD c's L2).
__global__ __launch_bounds__(256) void deg8_kernel(
    const int* __restrict__ src, const int* __restrict__ dst,
    int* __restrict__ dgo8, int* __restrict__ dgc, int N, int E) {
  int i = blockIdx.x * blockDim.x + threadIdx.x;
  const int S = gridDim.x * blockDim.x;
  for (; i < E; i += S) {
    const int c = (i >> 8) & 7;
    atomicAdd(&dgo8[c * N + src[i]], 1);
    atomicAdd(&dgc[c * N + dst[i]], 1);
  }
}

// per-node: totals across 8 copies -> norms + total in-degree
__global__ void norm_reduce_kernel(const int* __restrict__ dgo8, const int* __restrict__ dgc,
                                   float* __restrict__ no, float* __restrict__ ni,
                                   int* __restrict__ dgi_tot, int N) {
  int v = blockIdx.x * blockDim.x + threadIdx.x;
  if (v >= N) return;
  int so = 0, si = 0;
#pragma unroll
  for (int c = 0; c < 8; ++c) {
    so += dgo8[c * N + v];
    si += dgc[c * N + v];
  }
  no[v] = rsqrtf(fmaxf((float)so, 1.0f));
  ni[v] = rsqrtf(fmaxf((float)si, 1.0f));
  dgi_tot[v] = si;
}

// ---------------- 3-phase multi-block exclusive scan (256 blocks) ---------
__global__ __launch_bounds__(256) void scan_phaseA(const int* __restrict__ deg,
                                                   int* __restrict__ partial, int N) {
  __shared__ int red[256];
  const int chunkB = (N + gridDim.x - 1) / gridDim.x;
  const int lo = blockIdx.x * chunkB;
  const int hi = min(lo + chunkB, N);
  int s = 0;
  for (int i = lo + threadIdx.x; i < hi; i += 256) s += deg[i];
  red[threadIdx.x] = s;
  __syncthreads();
  for (int off = 128; off > 0; off >>= 1) {
    if (threadIdx.x < off) red[threadIdx.x] += red[threadIdx.x + off];
    __syncthreads();
  }
  if (threadIdx.x == 0) partial[blockIdx.x] = red[0];
}

__global__ __launch_bounds__(256) void scan_phaseB(const int* __restrict__ partial,
                                                   int* __restrict__ offsets) {
  __shared__ int psum[256];
  const int t = threadIdx.x;
  const int v = partial[t];
  psum[t] = v;
  __syncthreads();
  for (int off = 1; off < 256; off <<= 1) {
    int x = (t >= off) ? psum[t - off] : 0;
    __syncthreads();
    psum[t] += x;
    __syncthreads();
  }
  offsets[t] = psum[t] - v;  // exclusive
}

__global__ __launch_bounds__(256) void scan_phaseC(const int* __restrict__ deg,
                                                   const int* __restrict__ offsets,
                                                   int* __restrict__ row_start, int N, int E) {
  __shared__ int psum[256];
  const int chunkB = (N + gridDim.x - 1) / gridDim.x;
  const int lo0 = blockIdx.x * chunkB;
  const int hi0 = min(lo0 + chunkB, N);
  const int per = (chunkB + 255) >> 8;
  const int lo = lo0 + threadIdx.x * per;
  const int hi = min(lo + per, hi0);
  int s = 0;
  for (int i = lo; i < hi; ++i) s += deg[i];
  psum[threadIdx.x] = s;
  __syncthreads();
  for (int off = 1; off < 256; off <<= 1) {
    int x = (threadIdx.x >= off) ? psum[threadIdx.x - off] : 0;
    __syncthreads();
    psum[threadIdx.x] += x;
    __syncthreads();
  }
  int run = offsets[blockIdx.x] + psum[threadIdx.x] - s;
  for (int i = lo; i < hi; ++i) { row_start[i] = run; run += deg[i]; }
  if (blockIdx.x == 0 && threadIdx.x == 0) row_start[N] = E;
}

// per-node: cursor[c][v] = absolute start of segment (v,c)
__global__ void cursor_init_kernel(const int* __restrict__ row_st, const int* __restrict__ dgc,
                                   int* __restrict__ cursor, int N) {
  int v = blockIdx.x * blockDim.x + threadIdx.x;
  if (v >= N) return;
  int run = row_st[v];
#pragma unroll
  for (int c = 0; c < 8; ++c) {
    cursor[c * N + v] = run;
    run += dgc[c * N + v];
  }
}

__global__ __launch_bounds__(256) void fill8_kernel(
    const int* __restrict__ src, const int* __restrict__ dst,
    int* __restrict__ cursor, int* __restrict__ edge_src, int N, int E) {
  int i = blockIdx.x * blockDim.x + threadIdx.x;
  const int S = gridDim.x * blockDim.x;
  for (; i < E; i += S) {
    const int c = (i >> 8) & 7;
    int pos = atomicAdd(&cursor[c * N + dst[i]], 1);
    edge_src[pos] = src[i];
  }
}

// ===================== weight transpose + bf16 convert ====================
__global__ void wconv_kernel(const float* __restrict__ W, unsigned short* __restrict__ Wt,
                             int K, int C) {
  int i = blockIdx.x * blockDim.x + threadIdx.x;
  if (i < K * C) {
    int k = i / C, c = i - k * C;
    Wt[c * K + k] = f2bf(W[i]);
  }
}

// ============= feats f32 -> bf16 with norm_o fold: out = no[r]*F[r][c] ====
__global__ __launch_bounds__(256) void featconv_kernel(const float* __restrict__ F,
                                                       const float* __restrict__ no,
                                                       unsigned short* __restrict__ out, int N) {
  int row = blockIdx.x * 8 + (threadIdx.x >> 5);
  if (row >= N) return;
  int c = (threadIdx.x & 31) * 4;
  float4 v = *reinterpret_cast<const float4*>(F + (size_t)row * 128 + c);
  float nof = no[row];
  unsigned int lo = (unsigned int)f2bf(v.x * nof) | ((unsigned int)f2bf(v.y * nof) << 16);
  unsigned int hi = (unsigned int)f2bf(v.z * nof) | ((unsigned int)f2bf(v.w * nof) << 16);
  uint2 p = {lo, hi};
  *reinterpret_cast<uint2*>(out + (size_t)row * 128 + c) = p;
}

// ================== per-node gather aggregation (bf16) ====================
__global__ __launch_bounds__(256) void gather_agg_b(
    const unsigned short* __restrict__ hB, const int* __restrict__ row_start,
    const int* __restrict__ edge_src, const float* __restrict__ ni,
    unsigned short* __restrict__ aggB, int N) {
  const int v = blockIdx.x * 4 + (threadIdx.x >> 6);
  if (v >= N) return;
  const int lane = threadIdx.x & 63;
  const int s = row_start[v];
  const int e = row_start[v + 1];
  float a0 = 0.f, a1 = 0.f, b0 = 0.f, b1 = 0.f;
  float c0 = 0.f, c1 = 0.f, d0 = 0.f, d1 = 0.f;
  int j = s;
  for (; j + 4 <= e; j += 4) {
    int u0 = edge_src[j], u1 = edge_src[j + 1], u2 = edge_src[j + 2], u3 = edge_src[j + 3];
    unsigned int p0 = *reinterpret_cast<const unsigned int*>(hB + (size_t)u0 * 128 + 2 * lane);
    unsigned int p1 = *reinterpret_cast<const unsigned int*>(hB + (size_t)u1 * 128 + 2 * lane);
    unsigned int p2 = *reinterpret_cast<const unsigned int*>(hB + (size_t)u2 * 128 + 2 * lane);
    unsigned int p3 = *reinterpret_cast<const unsigned int*>(hB + (size_t)u3 * 128 + 2 * lane);
    a0 += bflo(p0); a1 += bfhi(p0);
    b0 += bflo(p1); b1 += bfhi(p1);
    c0 += bflo(p2); c1 += bfhi(p2);
    d0 += bflo(p3); d1 += bfhi(p3);
  }
  for (; j < e; ++j) {
    unsigned int p0 = *reinterpret_cast<const unsigned int*>(hB + (size_t)edge_src[j] * 128 + 2 * lane);
    a0 += bflo(p0); a1 += bfhi(p0);
  }
  const float niv = ni[v];
  a0 = ((a0 + b0) + (c0 + d0)) * niv;
  a1 = ((a1 + b1) + (c1 + d1)) * niv;
  unsigned int po = (unsigned int)f2bf(a0) | ((unsigned int)f2bf(a1) << 16);
  *reinterpret_cast<unsigned int*>(aggB + (size_t)v * 128 + 2 * lane) = po;
}

// ====== MFMA matmul [N,128]x[128,128] + bias + LN + ReLU + no-fold ========
__global__ __launch_bounds__(256) void mm_mfma_ln(
    const unsigned short* __restrict__ A, const unsigned short* __restrict__ Wt,
    const float* __restrict__ b, const float* __restrict__ g,
    const float* __restrict__ be, const float* __restrict__ no,
    unsigned short* __restrict__ out, int N) {
  __shared__ float sS[2][2][16];
  __shared__ float sQ[2][2][16];
  __shared__ float sNo[32];
  const int rbase = blockIdx.x * 32;
  const int w = threadIdx.x >> 6;
  const int l = threadIdx.x & 63;
  const int rt = w & 1, ch = w >> 1;
  if (threadIdx.x < 32) sNo[threadIdx.x] = no[min(rbase + (int)threadIdx.x, N - 1)];
  const int arow = min(rbase + rt * 16 + (l & 15), N - 1);
  const int kof = (l >> 4) * 8;

  bf16x8 af[4];
  const unsigned short* ap = A + (size_t)arow * 128 + kof;
#pragma unroll
  for (int kk = 0; kk < 4; ++kk)
    af[kk] = *reinterpret_cast<const bf16x8*>(ap + kk * 32);

  f32x4 acc[4] = {};
#pragma unroll
  for (int ct = 0; ct < 4; ++ct) {
    const int ccol = ch * 64 + ct * 16 + (l & 15);
    const unsigned short* bp = Wt + (size_t)ccol * 128 + kof;
#pragma unroll
    for (int kk = 0; kk < 4; ++kk) {
      bf16x8 bfr = *reinterpret_cast<const bf16x8*>(bp + kk * 32);
      acc[ct] = __builtin_amdgcn_mfma_f32_16x16x32_bf16(af[kk], bfr, acc[ct], 0, 0, 0);
    }
  }

  float s[4] = {0.f, 0.f, 0.f, 0.f}, q[4] = {0.f, 0.f, 0.f, 0.f};
#pragma unroll
  for (int ct = 0; ct < 4; ++ct) {
    const float bc = b[ch * 64 + ct * 16 + (l & 15)];
#pragma unroll
    for (int j = 0; j < 4; ++j) {
      float v = acc[ct][j] + bc;
      acc[ct][j] = v;
      s[j] += v;
      q[j] += v * v;
    }
  }
#pragma unroll
  for (int j = 0; j < 4; ++j) {
#pragma unroll
    for (int off = 1; off < 16; off <<= 1) {
      s[j] += __shfl_xor(s[j], off);
      q[j] += __shfl_xor(q[j], off);
    }
  }
  const int grp = l >> 4;
  if ((l & 15) == 0) {
#pragma unroll
    for (int j = 0; j < 4; ++j) {
      sS[rt][ch][grp * 4 + j] = s[j];
      sQ[rt][ch][grp * 4 + j] = q[j];
    }
  }
  __syncthreads();

#pragma unroll
  for (int j = 0; j < 4; ++j) {
    const int r = grp * 4 + j;
    const int row = rbase + rt * 16 + r;
    float S = sS[rt][0][r] + sS[rt][1][r];
    float Q = sQ[rt][0][r] + sQ[rt][1][r];
    float mu = S * (1.f / 128.f);
    float rstd = rsqrtf(fmaxf(Q * (1.f / 128.f) - mu * mu, 0.f) + LN_EPS);
    float nof = sNo[rt * 16 + r];
    if (row < N) {
#pragma unroll
      for (int ct = 0; ct < 4; ++ct) {
        const int ccol = ch * 64 + ct * 16 + (l & 15);
        float y = (acc[ct][j] - mu) * rstd * g[ccol] + be[ccol];
        y = fmaxf(y, 0.f) * nof;
        out[(size_t)row * 128 + ccol] = f2bf(y);
      }
    }
  }
}

// ============ final MFMA matmul [N,128]x[128,64] + bias -> f32 out ========
__global__ __launch_bounds__(256) void mm_final_mfma(
    const unsigned short* __restrict__ A, const unsigned short* __restrict__ Wt,
    const float* __restrict__ b, float* __restrict__ out, int N) {
  const int rbase = blockIdx.x * 32;
  const int w = threadIdx.x >> 6;
  const int l = threadIdx.x & 63;
  const int rt = w & 1, ch = w >> 1;
  const int arow = min(rbase + rt * 16 + (l & 15), N - 1);
  const int kof = (l >> 4) * 8;

  bf16x8 af[4];
  const unsigned short* ap = A + (size_t)arow * 128 + kof;
#pragma unroll
  for (int kk = 0; kk < 4; ++kk)
    af[kk] = *reinterpret_cast<const bf16x8*>(ap + kk * 32);

  f32x4 acc[2] = {};
#pragma unroll
  for (int ct = 0; ct < 2; ++ct) {
    const int ccol = ch * 32 + ct * 16 + (l & 15);
    const unsigned short* bp = Wt + (size_t)ccol * 128 + kof;
#pragma unroll
    for (int kk = 0; kk < 4; ++kk) {
      bf16x8 bfr = *reinterpret_cast<const bf16x8*>(bp + kk * 32);
      acc[ct] = __builtin_amdgcn_mfma_f32_16x16x32_bf16(af[kk], bfr, acc[ct], 0, 0, 0);
    }
  }
  const int grp = l >> 4;
#pragma unroll
  for (int ct = 0; ct < 2; ++ct) {
    const int ccol = ch * 32 + ct * 16 + (l & 15);
    const float bc = b[ccol];
#pragma unroll
    for (int j = 0; j < 4; ++j) {
      const int row = rbase + rt * 16 + grp * 4 + j;
      if (row < N) out[(size_t)row * 64 + ccol] = acc[ct][j] + bc;
    }
  }
}

extern "C" void kernel_launch(void* const* d_in, const int* in_sizes, int n_in,
                              void* d_out, int out_size, void* d_ws, size_t ws_size,
                              hipStream_t stream) {
  const float* feats = (const float*)d_in[0];
  const int*   src   = (const int*)d_in[1];
  const int*   dst   = (const int*)d_in[2];
  const float* W0    = (const float*)d_in[3];
  const float* b0    = (const float*)d_in[4];
  const float* g0    = (const float*)d_in[5];
  const float* be0   = (const float*)d_in[6];
  const float* W1    = (const float*)d_in[7];
  const float* b1    = (const float*)d_in[8];
  const float* g1    = (const float*)d_in[9];
  const float* be1   = (const float*)d_in[10];
  const float* W2    = (const float*)d_in[11];
  const float* b2    = (const float*)d_in[12];
  float* out = (float*)d_out;

  const int n = in_sizes[0] / 128;  // 100000
  const int e = in_sizes[1];        // 1600000

  float* ws = (float*)d_ws;
  auto pad4 = [](size_t x) { return (x + 3) & ~(size_t)3; };
  size_t o = 0;
  float* norm_o  = ws + o; o = pad4(o + n);
  float* norm_i  = ws + o; o = pad4(o + n);
  int*   dgo8    = (int*)(ws + o); o = pad4(o + (size_t)8 * n);  // reused as cursor
  int*   dgc     = (int*)(ws + o); o = pad4(o + (size_t)8 * n);
  int*   dgi_tot = (int*)(ws + o); o = pad4(o + n);
  int*   row_st  = (int*)(ws + o); o = pad4(o + n + 1);
  int*   partial = (int*)(ws + o); o = pad4(o + 256);
  int*   offsets = (int*)(ws + o); o = pad4(o + 256);
  int*   edg_src = (int*)(ws + o); o = pad4(o + (size_t)e);
  unsigned short* featB = (unsigned short*)(ws + o); o = pad4(o + (size_t)n * 64);  // also hB
  unsigned short* aggB  = (unsigned short*)(ws + o); o = pad4(o + (size_t)n * 64);
  unsigned short* Wt0   = (unsigned short*)(ws + o); o = pad4(o + 128 * 128 / 2);
  unsigned short* Wt1   = (unsigned short*)(ws + o); o = pad4(o + 128 * 128 / 2);
  unsigned short* Wt2   = (unsigned short*)(ws + o); o = pad4(o + 128 * 64 / 2);
  int* cursor = dgo8;              // dgo8 dead after norm_reduce
  unsigned short* hB = featB;      // featB dead after layer-0 gather

  // ---- CSR build (8-way privatized) ----
  hipMemsetAsync(dgo8, 0, (size_t)16 * n * sizeof(int), stream);  // dgo8 + dgc
  deg8_kernel<<<2048, 256, 0, stream>>>(src, dst, dgo8, dgc, n, e);
  norm_reduce_kernel<<<(n + 255) / 256, 256, 0, stream>>>(dgo8, dgc, norm_o, norm_i, dgi_tot, n);
  scan_phaseA<<<256, 256, 0, stream>>>(dgi_tot, partial, n);
  scan_phaseB<<<1, 256, 0, stream>>>(partial, offsets);
  scan_phaseC<<<256, 256, 0, stream>>>(dgi_tot, offsets, row_st, n, e);
  cursor_init_kernel<<<(n + 255) / 256, 256, 0, stream>>>(row_st, dgc, cursor, n);
  fill8_kernel<<<2048, 256, 0, stream>>>(src, dst, cursor, edg_src, n, e);

  // ---- weights -> bf16 transposed; feats -> bf16 with no-fold ----
  wconv_kernel<<<(128 * 128 + 255) / 256, 256, 0, stream>>>(W0, Wt0, 128, 128);
  wconv_kernel<<<(128 * 128 + 255) / 256, 256, 0, stream>>>(W1, Wt1, 128, 128);
  wconv_kernel<<<(128 * 64 + 255) / 256, 256, 0, stream>>>(W2, Wt2, 128, 64);
  featconv_kernel<<<(n + 7) / 8, 256, 0, stream>>>(feats, norm_o, featB, n);

  const int gblocks = (n + 3) / 4;
  const int mblocks = (n + 31) / 32;

  // layer 0
  gather_agg_b<<<gblocks, 256, 0, stream>>>(featB, row_st, edg_src, norm_i, aggB, n);
  mm_mfma_ln<<<mblocks, 256, 0, stream>>>(aggB, Wt0, b0, g0, be0, norm_o, hB, n);
  // layer 1
  gather_agg_b<<<gblocks, 256, 0, stream>>>(hB, row_st, edg_src, norm_i, aggB, n);
  mm_mfma_ln<<<mblocks, 256, 0, stream>>>(aggB, Wt1, b1, g1, be1, norm_o, hB, n);
  // final layer
  gather_agg_b<<<gblocks, 256, 0, stream>>>(hB, row_st, edg_src, norm_i, aggB, n);
  mm_final_mfma<<<mblocks, 256, 0, stream>>>(aggB, Wt2, b2, out, n);
}

// Round 6
// 588.190 us; speedup vs baseline: 1.0783x; 1.0783x over previous
//
#include <hip/hip_runtime.h>

constexpr float LN_EPS = 1e-5f;

typedef __bf16 bf16x8 __attribute__((ext_vector_type(8)));
typedef float f32x4 __attribute__((ext_vector_type(4)));

__device__ __forceinline__ unsigned short f2bf(float f) {
  unsigned int u = __float_as_uint(f);
  u = (u + 0x7fffu + ((u >> 16) & 1u)) >> 16;  // RNE
  return (unsigned short)u;
}
__device__ __forceinline__ float bflo(unsigned int p) { return __uint_as_float(p << 16); }
__device__ __forceinline__ float bfhi(unsigned int p) { return __uint_as_float(p & 0xffff0000u); }

#define NPB 256  // nodes per bucket (bucket = dst >> 8)

// ============ passA: bucket counts (LDS) + privatized out-degree ==========
// copy index c=(i>>8)&7 == blockIdx&7 when gridDim%8==0 (consistent w/ passB)
__global__ __launch_bounds__(256) void passA_kernel(
    const int* __restrict__ src, const int* __restrict__ dst,
    int* __restrict__ dgo8, int* __restrict__ cnt8, int NB, int N, int E) {
  extern __shared__ int hist[];  // NB ints
  for (int j = threadIdx.x; j < NB; j += 256) hist[j] = 0;
  __syncthreads();
  const int c = blockIdx.x & 7;
  int i = blockIdx.x * 256 + threadIdx.x;
  const int S = gridDim.x * 256;
  for (; i < E; i += S) {
    atomicAdd(&dgo8[c * N + src[i]], 1);
    atomicAdd(&hist[dst[i] >> 8], 1);
  }
  __syncthreads();
  for (int j = threadIdx.x; j < NB; j += 256) {
    int v = hist[j];
    if (v) atomicAdd(&cnt8[c * NB + j], v);
  }
}

// ====== bucket_scan: bucket_start (excl scan of totals) + per-copy cursors =
__global__ __launch_bounds__(1024) void bucket_scan_kernel(
    const int* __restrict__ cnt8, int* __restrict__ bucket_start,
    int* __restrict__ cur8, int* __restrict__ row_st, int NB, int N, int E) {
  __shared__ int psum[1024];
  const int t = threadIdx.x;
  int tot = 0;
  if (t < NB) {
#pragma unroll
    for (int c = 0; c < 8; ++c) tot += cnt8[c * NB + t];
  }
  psum[t] = tot;
  __syncthreads();
  for (int off = 1; off < 1024; off <<= 1) {
    int x = (t >= off) ? psum[t - off] : 0;
    __syncthreads();
    psum[t] += x;
    __syncthreads();
  }
  if (t < NB) {
    int bs = psum[t] - tot;  // exclusive
    bucket_start[t] = bs;
    int run = bs;
#pragma unroll
    for (int c = 0; c < 8; ++c) {
      cur8[c * NB + t] = run;
      run += cnt8[c * NB + t];
    }
  }
  if (t == 0) {
    bucket_start[NB] = E;
    row_st[N] = E;
  }
}

// ============ passB: partition edges into buckets (packed src|dstLow) =====
__global__ __launch_bounds__(256) void passB_kernel(
    const int* __restrict__ src, const int* __restrict__ dst,
    int* __restrict__ cur8, unsigned int* __restrict__ packed, int NB, int E) {
  const int c = blockIdx.x & 7;
  int i = blockIdx.x * 256 + threadIdx.x;
  const int S = gridDim.x * 256;
  for (; i < E; i += S) {
    const int d = dst[i];
    int pos = atomicAdd(&cur8[c * NB + (d >> 8)], 1);
    packed[pos] = ((unsigned int)(d & 255) << 24) | (unsigned int)src[i];
  }
}

// ===== passC: per-bucket local CSR (row_st, norm_i, sorted edge_src) ======
__global__ __launch_bounds__(256) void passC_kernel(
    const unsigned int* __restrict__ packed, const int* __restrict__ bucket_start,
    int* __restrict__ row_st, float* __restrict__ ni,
    int* __restrict__ edge_src, int N) {
  __shared__ int cnt[NPB];
  __shared__ int cur[NPB];
  const int b = blockIdx.x;
  const int t = threadIdx.x;
  const int v0 = b * NPB;
  const int bs = bucket_start[b];
  const int be = bucket_start[b + 1];
  cnt[t] = 0;
  __syncthreads();
  for (int i = bs + t; i < be; i += 256)
    atomicAdd(&cnt[packed[i] >> 24], 1);
  __syncthreads();
  // exclusive scan of cnt into cur
  int own = cnt[t];
  int incl = own;
  __shared__ int tmp[NPB];
  tmp[t] = incl;
  __syncthreads();
  for (int off = 1; off < NPB; off <<= 1) {
    int x = (t >= off) ? tmp[t - off] : 0;
    __syncthreads();
    tmp[t] += x;
    __syncthreads();
  }
  const int pref = tmp[t] - own;
  if (v0 + t < N) {
    row_st[v0 + t] = bs + pref;
    ni[v0 + t] = rsqrtf(fmaxf((float)own, 1.0f));
  }
  cur[t] = bs + pref;
  __syncthreads();
  for (int i = bs + t; i < be; i += 256) {
    unsigned int p = packed[i];
    int pos = atomicAdd(&cur[p >> 24], 1);
    edge_src[pos] = (int)(p & 0xFFFFFFu);
  }
}

// ================ norm_o from 8-way privatized out-degree =================
__global__ void norm_o_kernel(const int* __restrict__ dgo8, float* __restrict__ no, int N) {
  int v = blockIdx.x * blockDim.x + threadIdx.x;
  if (v >= N) return;
  int s = 0;
#pragma unroll
  for (int c = 0; c < 8; ++c) s += dgo8[c * N + v];
  no[v] = rsqrtf(fmaxf((float)s, 1.0f));
}

// ===================== weight transpose + bf16 convert ====================
__global__ void wconv_kernel(const float* __restrict__ W, unsigned short* __restrict__ Wt,
                             int K, int C) {
  int i = blockIdx.x * blockDim.x + threadIdx.x;
  if (i < K * C) {
    int k = i / C, c = i - k * C;
    Wt[c * K + k] = f2bf(W[i]);
  }
}

// ============= feats f32 -> bf16 with norm_o fold: out = no[r]*F[r][c] ====
__global__ __launch_bounds__(256) void featconv_kernel(const float* __restrict__ F,
                                                       const float* __restrict__ no,
                                                       unsigned short* __restrict__ out, int N) {
  int row = blockIdx.x * 8 + (threadIdx.x >> 5);
  if (row >= N) return;
  int c = (threadIdx.x & 31) * 4;
  float4 v = *reinterpret_cast<const float4*>(F + (size_t)row * 128 + c);
  float nof = no[row];
  unsigned int lo = (unsigned int)f2bf(v.x * nof) | ((unsigned int)f2bf(v.y * nof) << 16);
  unsigned int hi = (unsigned int)f2bf(v.z * nof) | ((unsigned int)f2bf(v.w * nof) << 16);
  uint2 p = {lo, hi};
  *reinterpret_cast<uint2*>(out + (size_t)row * 128 + c) = p;
}

// ================== per-node gather aggregation (bf16) ====================
__global__ __launch_bounds__(256) void gather_agg_b(
    const unsigned short* __restrict__ hB, const int* __restrict__ row_start,
    const int* __restrict__ edge_src, const float* __restrict__ ni,
    unsigned short* __restrict__ aggB, int N) {
  const int v = blockIdx.x * 4 + (threadIdx.x >> 6);
  if (v >= N) return;
  const int lane = threadIdx.x & 63;
  const int s = row_start[v];
  const int e = row_start[v + 1];
  float a0 = 0.f, a1 = 0.f, b0 = 0.f, b1 = 0.f;
  float c0 = 0.f, c1 = 0.f, d0 = 0.f, d1 = 0.f;
  int j = s;
  for (; j + 4 <= e; j += 4) {
    int u0 = edge_src[j], u1 = edge_src[j + 1], u2 = edge_src[j + 2], u3 = edge_src[j + 3];
    unsigned int p0 = *reinterpret_cast<const unsigned int*>(hB + (size_t)u0 * 128 + 2 * lane);
    unsigned int p1 = *reinterpret_cast<const unsigned int*>(hB + (size_t)u1 * 128 + 2 * lane);
    unsigned int p2 = *reinterpret_cast<const unsigned int*>(hB + (size_t)u2 * 128 + 2 * lane);
    unsigned int p3 = *reinterpret_cast<const unsigned int*>(hB + (size_t)u3 * 128 + 2 * lane);
    a0 += bflo(p0); a1 += bfhi(p0);
    b0 += bflo(p1); b1 += bfhi(p1);
    c0 += bflo(p2); c1 += bfhi(p2);
    d0 += bflo(p3); d1 += bfhi(p3);
  }
  for (; j < e; ++j) {
    unsigned int p0 = *reinterpret_cast<const unsigned int*>(hB + (size_t)edge_src[j] * 128 + 2 * lane);
    a0 += bflo(p0); a1 += bfhi(p0);
  }
  const float niv = ni[v];
  a0 = ((a0 + b0) + (c0 + d0)) * niv;
  a1 = ((a1 + b1) + (c1 + d1)) * niv;
  unsigned int po = (unsigned int)f2bf(a0) | ((unsigned int)f2bf(a1) << 16);
  *reinterpret_cast<unsigned int*>(aggB + (size_t)v * 128 + 2 * lane) = po;
}

// ====== MFMA matmul [N,128]x[128,128] + bias + LN + ReLU + no-fold ========
__global__ __launch_bounds__(256) void mm_mfma_ln(
    const unsigned short* __restrict__ A, const unsigned short* __restrict__ Wt,
    const float* __restrict__ b, const float* __restrict__ g,
    const float* __restrict__ be, const float* __restrict__ no,
    unsigned short* __restrict__ out, int N) {
  __shared__ float sS[2][2][16];
  __shared__ float sQ[2][2][16];
  __shared__ float sNo[32];
  const int rbase = blockIdx.x * 32;
  const int w = threadIdx.x >> 6;
  const int l = threadIdx.x & 63;
  const int rt = w & 1, ch = w >> 1;
  if (threadIdx.x < 32) sNo[threadIdx.x] = no[min(rbase + (int)threadIdx.x, N - 1)];
  const int arow = min(rbase + rt * 16 + (l & 15), N - 1);
  const int kof = (l >> 4) * 8;

  bf16x8 af[4];
  const unsigned short* ap = A + (size_t)arow * 128 + kof;
#pragma unroll
  for (int kk = 0; kk < 4; ++kk)
    af[kk] = *reinterpret_cast<const bf16x8*>(ap + kk * 32);

  f32x4 acc[4] = {};
#pragma unroll
  for (int ct = 0; ct < 4; ++ct) {
    const int ccol = ch * 64 + ct * 16 + (l & 15);
    const unsigned short* bp = Wt + (size_t)ccol * 128 + kof;
#pragma unroll
    for (int kk = 0; kk < 4; ++kk) {
      bf16x8 bfr = *reinterpret_cast<const bf16x8*>(bp + kk * 32);
      acc[ct] = __builtin_amdgcn_mfma_f32_16x16x32_bf16(af[kk], bfr, acc[ct], 0, 0, 0);
    }
  }

  float s[4] = {0.f, 0.f, 0.f, 0.f}, q[4] = {0.f, 0.f, 0.f, 0.f};
#pragma unroll
  for (int ct = 0; ct < 4; ++ct) {
    const float bc = b[ch * 64 + ct * 16 + (l & 15)];
#pragma unroll
    for (int j = 0; j < 4; ++j) {
      float v = acc[ct][j] + bc;
      acc[ct][j] = v;
      s[j] += v;
      q[j] += v * v;
    }
  }
#pragma unroll
  for (int j = 0; j < 4; ++j) {
#pragma unroll
    for (int off = 1; off < 16; off <<= 1) {
      s[j] += __shfl_xor(s[j], off);
      q[j] += __shfl_xor(q[j], off);
    }
  }
  const int grp = l >> 4;
  if ((l & 15) == 0) {
#pragma unroll
    for (int j = 0; j < 4; ++j) {
      sS[rt][ch][grp * 4 + j] = s[j];
      sQ[rt][ch][grp * 4 + j] = q[j];
    }
  }
  __syncthreads();

#pragma unroll
  for (int j = 0; j < 4; ++j) {
    const int r = grp * 4 + j;
    const int row = rbase + rt * 16 + r;
    float S = sS[rt][0][r] + sS[rt][1][r];
    float Q = sQ[rt][0][r] + sQ[rt][1][r];
    float mu = S * (1.f / 128.f);
    float rstd = rsqrtf(fmaxf(Q * (1.f / 128.f) - mu * mu, 0.f) + LN_EPS);
    float nof = sNo[rt * 16 + r];
    if (row < N) {
#pragma unroll
      for (int ct = 0; ct < 4; ++ct) {
        const int ccol = ch * 64 + ct * 16 + (l & 15);
        float y = (acc[ct][j] - mu) * rstd * g[ccol] + be[ccol];
        y = fmaxf(y, 0.f) * nof;
        out[(size_t)row * 128 + ccol] = f2bf(y);
      }
    }
  }
}

// ============ final MFMA matmul [N,128]x[128,64] + bias -> f32 out ========
__global__ __launch_bounds__(256) void mm_final_mfma(
    const unsigned short* __restrict__ A, const unsigned short* __restrict__ Wt,
    const float* __restrict__ b, float* __restrict__ out, int N) {
  const int rbase = blockIdx.x * 32;
  const int w = threadIdx.x >> 6;
  const int l = threadIdx.x & 63;
  const int rt = w & 1, ch = w >> 1;
  const int arow = min(rbase + rt * 16 + (l & 15), N - 1);
  const int kof = (l >> 4) * 8;

  bf16x8 af[4];
  const unsigned short* ap = A + (size_t)arow * 128 + kof;
#pragma unroll
  for (int kk = 0; kk < 4; ++kk)
    af[kk] = *reinterpret_cast<const bf16x8*>(ap + kk * 32);

  f32x4 acc[2] = {};
#pragma unroll
  for (int ct = 0; ct < 2; ++ct) {
    const int ccol = ch * 32 + ct * 16 + (l & 15);
    const unsigned short* bp = Wt + (size_t)ccol * 128 + kof;
#pragma unroll
    for (int kk = 0; kk < 4; ++kk) {
      bf16x8 bfr = *reinterpret_cast<const bf16x8*>(bp + kk * 32);
      acc[ct] = __builtin_amdgcn_mfma_f32_16x16x32_bf16(af[kk], bfr, acc[ct], 0, 0, 0);
    }
  }
  const int grp = l >> 4;
#pragma unroll
  for (int ct = 0; ct < 2; ++ct) {
    const int ccol = ch * 32 + ct * 16 + (l & 15);
    const float bc = b[ccol];
#pragma unroll
    for (int j = 0; j < 4; ++j) {
      const int row = rbase + rt * 16 + grp * 4 + j;
      if (row < N) out[(size_t)row * 64 + ccol] = acc[ct][j] + bc;
    }
  }
}

extern "C" void kernel_launch(void* const* d_in, const int* in_sizes, int n_in,
                              void* d_out, int out_size, void* d_ws, size_t ws_size,
                              hipStream_t stream) {
  const float* feats = (const float*)d_in[0];
  const int*   src   = (const int*)d_in[1];
  const int*   dst   = (const int*)d_in[2];
  const float* W0    = (const float*)d_in[3];
  const float* b0    = (const float*)d_in[4];
  const float* g0    = (const float*)d_in[5];
  const float* be0   = (const float*)d_in[6];
  const float* W1    = (const float*)d_in[7];
  const float* b1    = (const float*)d_in[8];
  const float* g1    = (const float*)d_in[9];
  const float* be1   = (const float*)d_in[10];
  const float* W2    = (const float*)d_in[11];
  const float* b2    = (const float*)d_in[12];
  float* out = (float*)d_out;

  const int n = in_sizes[0] / 128;  // 100000
  const int e = in_sizes[1];        // 1600000
  const int NB = (n + NPB - 1) / NPB;  // buckets (391)

  float* ws = (float*)d_ws;
  auto pad4 = [](size_t x) { return (x + 3) & ~(size_t)3; };
  size_t o = 0;
  float* norm_o  = ws + o; o = pad4(o + n);
  float* norm_i  = ws + o; o = pad4(o + n);
  int*   dgo8    = (int*)(ws + o); o = pad4(o + (size_t)8 * n);
  int*   cnt8    = (int*)(ws + o); o = pad4(o + (size_t)8 * NB);   // zeroed with dgo8
  int*   cur8    = (int*)(ws + o); o = pad4(o + (size_t)8 * NB);
  int*   bkt_st  = (int*)(ws + o); o = pad4(o + NB + 1);
  int*   row_st  = (int*)(ws + o); o = pad4(o + n + 1);
  unsigned int* packed = (unsigned int*)(ws + o); o = pad4(o + (size_t)e);
  int*   edg_src = (int*)(ws + o); o = pad4(o + (size_t)e);
  unsigned short* featB = (unsigned short*)(ws + o); o = pad4(o + (size_t)n * 64);  // also hB
  unsigned short* aggB  = (unsigned short*)(ws + o); o = pad4(o + (size_t)n * 64);
  unsigned short* Wt0   = (unsigned short*)(ws + o); o = pad4(o + 128 * 128 / 2);
  unsigned short* Wt1   = (unsigned short*)(ws + o); o = pad4(o + 128 * 128 / 2);
  unsigned short* Wt2   = (unsigned short*)(ws + o); o = pad4(o + 128 * 64 / 2);
  unsigned short* hB = featB;  // featB dead after layer-0 gather

  // ---- CSR build: bucket partition ----
  hipMemsetAsync(dgo8, 0, ((size_t)8 * n + (size_t)8 * NB + 8) * sizeof(int), stream);
  passA_kernel<<<1024, 256, NB * sizeof(int), stream>>>(src, dst, dgo8, cnt8, NB, n, e);
  bucket_scan_kernel<<<1, 1024, 0, stream>>>(cnt8, bkt_st, cur8, row_st, NB, n, e);
  passB_kernel<<<2048, 256, 0, stream>>>(src, dst, cur8, packed, NB, e);
  passC_kernel<<<NB, 256, 0, stream>>>(packed, bkt_st, row_st, norm_i, edg_src, n);
  norm_o_kernel<<<(n + 255) / 256, 256, 0, stream>>>(dgo8, norm_o, n);

  // ---- weights -> bf16 transposed; feats -> bf16 with no-fold ----
  wconv_kernel<<<(128 * 128 + 255) / 256, 256, 0, stream>>>(W0, Wt0, 128, 128);
  wconv_kernel<<<(128 * 128 + 255) / 256, 256, 0, stream>>>(W1, Wt1, 128, 128);
  wconv_kernel<<<(128 * 64 + 255) / 256, 256, 0, stream>>>(W2, Wt2, 128, 64);
  featconv_kernel<<<(n + 7) / 8, 256, 0, stream>>>(feats, norm_o, featB, n);

  const int gblocks = (n + 3) / 4;
  const int mblocks = (n + 31) / 32;

  // layer 0
  gather_agg_b<<<gblocks, 256, 0, stream>>>(featB, row_st, edg_src, norm_i, aggB, n);
  mm_mfma_ln<<<mblocks, 256, 0, stream>>>(aggB, Wt0, b0, g0, be0, norm_o, hB, n);
  // layer 1
  gather_agg_b<<<gblocks, 256, 0, stream>>>(hB, row_st, edg_src, norm_i, aggB, n);
  mm_mfma_ln<<<mblocks, 256, 0, stream>>>(aggB, Wt1, b1, g1, be1, norm_o, hB, n);
  // final layer
  gather_agg_b<<<gblocks, 256, 0, stream>>>(hB, row_st, edg_src, norm_i, aggB, n);
  mm_final_mfma<<<mblocks, 256, 0, stream>>>(aggB, Wt2, b2, out, n);
}

// Round 7
// 431.542 us; speedup vs baseline: 1.4697x; 1.3630x over previous
//
#include <hip/hip_runtime.h>

constexpr float LN_EPS = 1e-5f;

typedef __bf16 bf16x8 __attribute__((ext_vector_type(8)));
typedef float f32x4 __attribute__((ext_vector_type(4)));

__device__ __forceinline__ unsigned short f2bf(float f) {
  unsigned int u = __float_as_uint(f);
  u = (u + 0x7fffu + ((u >> 16) & 1u)) >> 16;  // RNE
  return (unsigned short)u;
}
__device__ __forceinline__ float bflo(unsigned int p) { return __uint_as_float(p << 16); }
__device__ __forceinline__ float bfhi(unsigned int p) { return __uint_as_float(p & 0xffff0000u); }

#define NPB 256    // nodes per bucket (bucket = node >> 8)
#define CHUNK 4096 // edges per partition block

// ======== passA: per-chunk LDS histograms (dst-bucket & src-bucket) =======
// NO global atomics: block blk writes cnt[b*NBLK + blk] for all b.
__global__ __launch_bounds__(256) void passA_kernel(
    const int* __restrict__ src, const int* __restrict__ dst,
    int* __restrict__ cntD, int* __restrict__ cntS, int NB, int NBLK, int E) {
  extern __shared__ int sh[];  // 2*NB
  for (int j = threadIdx.x; j < 2 * NB; j += 256) sh[j] = 0;
  __syncthreads();
  const int blk = blockIdx.x;
  const int base = blk * CHUNK;
  const int end = min(base + CHUNK, E);
  for (int i = base + threadIdx.x; i < end; i += 256) {
    atomicAdd(&sh[dst[i] >> 8], 1);
    atomicAdd(&sh[NB + (src[i] >> 8)], 1);
  }
  __syncthreads();
  for (int j = threadIdx.x; j < NB; j += 256) {
    cntD[j * NBLK + blk] = sh[j];
    cntS[j * NBLK + blk] = sh[NB + j];
  }
}

// ==== scan1: per-bucket exclusive scan over blocks (grid = 2*NB blocks) ===
__global__ __launch_bounds__(512) void scan1_kernel(
    const int* __restrict__ cntD, const int* __restrict__ cntS,
    int* __restrict__ offLD, int* __restrict__ offLS,
    int* __restrict__ totD, int* __restrict__ totS, int NB, int NBLK) {
  __shared__ int p[512];
  const int t = threadIdx.x;
  const bool isS = blockIdx.x >= NB;
  const int b = isS ? blockIdx.x - NB : blockIdx.x;
  const int* cnt = isS ? cntS : cntD;
  int* offL = isS ? offLS : offLD;
  int own = (t < NBLK) ? cnt[b * NBLK + t] : 0;
  p[t] = own;
  __syncthreads();
  for (int off = 1; off < 512; off <<= 1) {
    int x = (t >= off) ? p[t - off] : 0;
    __syncthreads();
    p[t] += x;
    __syncthreads();
  }
  if (t < NBLK) offL[b * NBLK + t] = p[t] - own;
  if (t == 511) (isS ? totS : totD)[b] = p[511];
}

// ==== scan2: exclusive scan of bucket totals -> bucket_start (1 block) ====
__global__ __launch_bounds__(512) void scan2_kernel(
    const int* __restrict__ totD, const int* __restrict__ totS,
    int* __restrict__ bktD, int* __restrict__ bktS,
    int* __restrict__ row_st, int NB, int N, int E) {
  __shared__ int p[512];
  const int t = threadIdx.x;
  int own = (t < NB) ? totD[t] : 0;
  p[t] = own;
  __syncthreads();
  for (int off = 1; off < 512; off <<= 1) {
    int x = (t >= off) ? p[t - off] : 0;
    __syncthreads();
    p[t] += x;
    __syncthreads();
  }
  if (t < NB) bktD[t] = p[t] - own;
  __syncthreads();
  int own2 = (t < NB) ? totS[t] : 0;
  p[t] = own2;
  __syncthreads();
  for (int off = 1; off < 512; off <<= 1) {
    int x = (t >= off) ? p[t - off] : 0;
    __syncthreads();
    p[t] += x;
    __syncthreads();
  }
  if (t < NB) bktS[t] = p[t] - own2;
  if (t == 0) {
    bktD[NB] = E;
    bktS[NB] = E;
    row_st[N] = E;
  }
}

// ======= passB: LDS counting-sort per chunk + coalesced group copy-out ====
__global__ __launch_bounds__(256) void passB_kernel(
    const int* __restrict__ src, const int* __restrict__ dst,
    const int* __restrict__ offLD, const int* __restrict__ offLS,
    const int* __restrict__ bkt_stD, const int* __restrict__ bkt_stS,
    unsigned int* __restrict__ packedD, unsigned char* __restrict__ srcS,
    int NB, int NBLK, int E) {
  __shared__ unsigned int sD[CHUNK];     // 16 KB sorted (dstLow<<24 | src)
  __shared__ unsigned short bD_[CHUNK];  // 8 KB bucket id per sorted slot
  __shared__ unsigned char sS_[CHUNK];   // 4 KB sorted srcLow
  __shared__ unsigned short bS_[CHUNK];  // 8 KB
  __shared__ int hD[512], lD[512], hS[512], lS[512];
  const int t = threadIdx.x;
  const int blk = blockIdx.x;
  const int base = blk * CHUNK;
  const int end = min(base + CHUNK, E);
  const int cnt = end - base;
  hD[t] = 0; hD[t + 256] = 0; hS[t] = 0; hS[t + 256] = 0;
  __syncthreads();
  // phase 1: local histograms
  for (int i = base + t; i < end; i += 256) {
    atomicAdd(&hD[dst[i] >> 8], 1);
    atomicAdd(&hS[src[i] >> 8], 1);
  }
  __syncthreads();
  // phase 2: exclusive scans (512 slots, 2 per thread)
  int oD0 = hD[t], oD1 = hD[t + 256], oS0 = hS[t], oS1 = hS[t + 256];
  for (int off = 1; off < 512; off <<= 1) {
    int xd0 = (t >= off) ? hD[t - off] : 0;
    int xd1 = (t + 256 >= off) ? hD[t + 256 - off] : 0;
    int xs0 = (t >= off) ? hS[t - off] : 0;
    int xs1 = (t + 256 >= off) ? hS[t + 256 - off] : 0;
    __syncthreads();
    hD[t] += xd0; hD[t + 256] += xd1;
    hS[t] += xs0; hS[t + 256] += xs1;
    __syncthreads();
  }
  lD[t] = hD[t] - oD0; lD[t + 256] = hD[t + 256] - oD1;
  lS[t] = hS[t] - oS0; lS[t + 256] = hS[t + 256] - oS1;
  __syncthreads();
  hD[t] = lD[t]; hD[t + 256] = lD[t + 256];  // running cursors
  hS[t] = lS[t]; hS[t + 256] = lS[t + 256];
  __syncthreads();
  // phase 3: scatter into LDS (local sort)
  for (int i = base + t; i < end; i += 256) {
    const int d = dst[i];
    const int s = src[i];
    const int bD = d >> 8;
    const int pD = atomicAdd(&hD[bD], 1);
    sD[pD] = ((unsigned int)(d & 255) << 24) | (unsigned int)s;
    bD_[pD] = (unsigned short)bD;
    const int bS = s >> 8;
    const int pS = atomicAdd(&hS[bS], 1);
    sS_[pS] = (unsigned char)(s & 255);
    bS_[pS] = (unsigned short)bS;
  }
  __syncthreads();
  // phase 4: coalesced copy-out to disjoint global windows
  for (int i = t; i < cnt; i += 256) {
    const int bD = bD_[i];
    packedD[bkt_stD[bD] + offLD[bD * NBLK + blk] + (i - lD[bD])] = sD[i];
    const int bS = bS_[i];
    srcS[bkt_stS[bS] + offLS[bS * NBLK + blk] + (i - lS[bS])] = sS_[i];
  }
}

// ===== passC: per-bucket local CSR (row_st, norm_i, sorted edge_src) ======
__global__ __launch_bounds__(256) void passC_kernel(
    const unsigned int* __restrict__ packed, const int* __restrict__ bucket_start,
    int* __restrict__ row_st, float* __restrict__ ni,
    int* __restrict__ edge_src, int N) {
  __shared__ int cnt[NPB];
  __shared__ int cur[NPB];
  __shared__ int tmp[NPB];
  const int b = blockIdx.x;
  const int t = threadIdx.x;
  const int v0 = b * NPB;
  const int bs = bucket_start[b];
  const int be = bucket_start[b + 1];
  cnt[t] = 0;
  __syncthreads();
  for (int i = bs + t; i < be; i += 256)
    atomicAdd(&cnt[packed[i] >> 24], 1);
  __syncthreads();
  int own = cnt[t];
  tmp[t] = own;
  __syncthreads();
  for (int off = 1; off < NPB; off <<= 1) {
    int x = (t >= off) ? tmp[t - off] : 0;
    __syncthreads();
    tmp[t] += x;
    __syncthreads();
  }
  const int pref = tmp[t] - own;
  if (v0 + t < N) {
    row_st[v0 + t] = bs + pref;
    ni[v0 + t] = rsqrtf(fmaxf((float)own, 1.0f));
  }
  cur[t] = bs + pref;
  __syncthreads();
  for (int i = bs + t; i < be; i += 256) {
    unsigned int p = packed[i];
    int pos = atomicAdd(&cur[p >> 24], 1);
    edge_src[pos] = (int)(p & 0xFFFFFFu);
  }
}

// ========= passD: per-src-bucket count -> norm_o (no global atomics) ======
__global__ __launch_bounds__(256) void passD_kernel(
    const unsigned char* __restrict__ srcS, const int* __restrict__ bkt_stS,
    float* __restrict__ no, int N) {
  __shared__ int cnt[NPB];
  const int b = blockIdx.x;
  const int t = threadIdx.x;
  cnt[t] = 0;
  __syncthreads();
  const int bs = bkt_stS[b];
  const int be = bkt_stS[b + 1];
  for (int i = bs + t; i < be; i += 256)
    atomicAdd(&cnt[srcS[i]], 1);
  __syncthreads();
  const int v = b * NPB + t;
  if (v < N) no[v] = rsqrtf(fmaxf((float)cnt[t], 1.0f));
}

// ===================== weight transpose + bf16 convert ====================
__global__ void wconv_kernel(const float* __restrict__ W, unsigned short* __restrict__ Wt,
                             int K, int C) {
  int i = blockIdx.x * blockDim.x + threadIdx.x;
  if (i < K * C) {
    int k = i / C, c = i - k * C;
    Wt[c * K + k] = f2bf(W[i]);
  }
}

// ============= feats f32 -> bf16 with norm_o fold: out = no[r]*F[r][c] ====
__global__ __launch_bounds__(256) void featconv_kernel(const float* __restrict__ F,
                                                       const float* __restrict__ no,
                                                       unsigned short* __restrict__ out, int N) {
  int row = blockIdx.x * 8 + (threadIdx.x >> 5);
  if (row >= N) return;
  int c = (threadIdx.x & 31) * 4;
  float4 v = *reinterpret_cast<const float4*>(F + (size_t)row * 128 + c);
  float nof = no[row];
  unsigned int lo = (unsigned int)f2bf(v.x * nof) | ((unsigned int)f2bf(v.y * nof) << 16);
  unsigned int hi = (unsigned int)f2bf(v.z * nof) | ((unsigned int)f2bf(v.w * nof) << 16);
  uint2 p = {lo, hi};
  *reinterpret_cast<uint2*>(out + (size_t)row * 128 + c) = p;
}

// ================== per-node gather aggregation (bf16) ====================
__global__ __launch_bounds__(256) void gather_agg_b(
    const unsigned short* __restrict__ hB, const int* __restrict__ row_start,
    const int* __restrict__ edge_src, const float* __restrict__ ni,
    unsigned short* __restrict__ aggB, int N) {
  const int v = blockIdx.x * 4 + (threadIdx.x >> 6);
  if (v >= N) return;
  const int lane = threadIdx.x & 63;
  const int s = row_start[v];
  const int e = row_start[v + 1];
  float a0 = 0.f, a1 = 0.f, b0 = 0.f, b1 = 0.f;
  float c0 = 0.f, c1 = 0.f, d0 = 0.f, d1 = 0.f;
  int j = s;
  for (; j + 4 <= e; j += 4) {
    int u0 = edge_src[j], u1 = edge_src[j + 1], u2 = edge_src[j + 2], u3 = edge_src[j + 3];
    unsigned int p0 = *reinterpret_cast<const unsigned int*>(hB + (size_t)u0 * 128 + 2 * lane);
    unsigned int p1 = *reinterpret_cast<const unsigned int*>(hB + (size_t)u1 * 128 + 2 * lane);
    unsigned int p2 = *reinterpret_cast<const unsigned int*>(hB + (size_t)u2 * 128 + 2 * lane);
    unsigned int p3 = *reinterpret_cast<const unsigned int*>(hB + (size_t)u3 * 128 + 2 * lane);
    a0 += bflo(p0); a1 += bfhi(p0);
    b0 += bflo(p1); b1 += bfhi(p1);
    c0 += bflo(p2); c1 += bfhi(p2);
    d0 += bflo(p3); d1 += bfhi(p3);
  }
  for (; j < e; ++j) {
    unsigned int p0 = *reinterpret_cast<const unsigned int*>(hB + (size_t)edge_src[j] * 128 + 2 * lane);
    a0 += bflo(p0); a1 += bfhi(p0);
  }
  const float niv = ni[v];
  a0 = ((a0 + b0) + (c0 + d0)) * niv;
  a1 = ((a1 + b1) + (c1 + d1)) * niv;
  unsigned int po = (unsigned int)f2bf(a0) | ((unsigned int)f2bf(a1) << 16);
  *reinterpret_cast<unsigned int*>(aggB + (size_t)v * 128 + 2 * lane) = po;
}

// ====== MFMA matmul [N,128]x[128,128] + bias + LN + ReLU + no-fold ========
__global__ __launch_bounds__(256) void mm_mfma_ln(
    const unsigned short* __restrict__ A, const unsigned short* __restrict__ Wt,
    const float* __restrict__ b, const float* __restrict__ g,
    const float* __restrict__ be, const float* __restrict__ no,
    unsigned short* __restrict__ out, int N) {
  __shared__ float sS[2][2][16];
  __shared__ float sQ[2][2][16];
  __shared__ float sNo[32];
  const int rbase = blockIdx.x * 32;
  const int w = threadIdx.x >> 6;
  const int l = threadIdx.x & 63;
  const int rt = w & 1, ch = w >> 1;
  if (threadIdx.x < 32) sNo[threadIdx.x] = no[min(rbase + (int)threadIdx.x, N - 1)];
  const int arow = min(rbase + rt * 16 + (l & 15), N - 1);
  const int kof = (l >> 4) * 8;

  bf16x8 af[4];
  const unsigned short* ap = A + (size_t)arow * 128 + kof;
#pragma unroll
  for (int kk = 0; kk < 4; ++kk)
    af[kk] = *reinterpret_cast<const bf16x8*>(ap + kk * 32);

  f32x4 acc[4] = {};
#pragma unroll
  for (int ct = 0; ct < 4; ++ct) {
    const int ccol = ch * 64 + ct * 16 + (l & 15);
    const unsigned short* bp = Wt + (size_t)ccol * 128 + kof;
#pragma unroll
    for (int kk = 0; kk < 4; ++kk) {
      bf16x8 bfr = *reinterpret_cast<const bf16x8*>(bp + kk * 32);
      acc[ct] = __builtin_amdgcn_mfma_f32_16x16x32_bf16(af[kk], bfr, acc[ct], 0, 0, 0);
    }
  }

  float s[4] = {0.f, 0.f, 0.f, 0.f}, q[4] = {0.f, 0.f, 0.f, 0.f};
#pragma unroll
  for (int ct = 0; ct < 4; ++ct) {
    const float bc = b[ch * 64 + ct * 16 + (l & 15)];
#pragma unroll
    for (int j = 0; j < 4; ++j) {
      float v = acc[ct][j] + bc;
      acc[ct][j] = v;
      s[j] += v;
      q[j] += v * v;
    }
  }
#pragma unroll
  for (int j = 0; j < 4; ++j) {
#pragma unroll
    for (int off = 1; off < 16; off <<= 1) {
      s[j] += __shfl_xor(s[j], off);
      q[j] += __shfl_xor(q[j], off);
    }
  }
  const int grp = l >> 4;
  if ((l & 15) == 0) {
#pragma unroll
    for (int j = 0; j < 4; ++j) {
      sS[rt][ch][grp * 4 + j] = s[j];
      sQ[rt][ch][grp * 4 + j] = q[j];
    }
  }
  __syncthreads();

#pragma unroll
  for (int j = 0; j < 4; ++j) {
    const int r = grp * 4 + j;
    const int row = rbase + rt * 16 + r;
    float S = sS[rt][0][r] + sS[rt][1][r];
    float Q = sQ[rt][0][r] + sQ[rt][1][r];
    float mu = S * (1.f / 128.f);
    float rstd = rsqrtf(fmaxf(Q * (1.f / 128.f) - mu * mu, 0.f) + LN_EPS);
    float nof = sNo[rt * 16 + r];
    if (row < N) {
#pragma unroll
      for (int ct = 0; ct < 4; ++ct) {
        const int ccol = ch * 64 + ct * 16 + (l & 15);
        float y = (acc[ct][j] - mu) * rstd * g[ccol] + be[ccol];
        y = fmaxf(y, 0.f) * nof;
        out[(size_t)row * 128 + ccol] = f2bf(y);
      }
    }
  }
}

// ============ final MFMA matmul [N,128]x[128,64] + bias -> f32 out ========
__global__ __launch_bounds__(256) void mm_final_mfma(
    const unsigned short* __restrict__ A, const unsigned short* __restrict__ Wt,
    const float* __restrict__ b, float* __restrict__ out, int N) {
  const int rbase = blockIdx.x * 32;
  const int w = threadIdx.x >> 6;
  const int l = threadIdx.x & 63;
  const int rt = w & 1, ch = w >> 1;
  const int arow = min(rbase + rt * 16 + (l & 15), N - 1);
  const int kof = (l >> 4) * 8;

  bf16x8 af[4];
  const unsigned short* ap = A + (size_t)arow * 128 + kof;
#pragma unroll
  for (int kk = 0; kk < 4; ++kk)
    af[kk] = *reinterpret_cast<const bf16x8*>(ap + kk * 32);

  f32x4 acc[2] = {};
#pragma unroll
  for (int ct = 0; ct < 2; ++ct) {
    const int ccol = ch * 32 + ct * 16 + (l & 15);
    const unsigned short* bp = Wt + (size_t)ccol * 128 + kof;
#pragma unroll
    for (int kk = 0; kk < 4; ++kk) {
      bf16x8 bfr = *reinterpret_cast<const bf16x8*>(bp + kk * 32);
      acc[ct] = __builtin_amdgcn_mfma_f32_16x16x32_bf16(af[kk], bfr, acc[ct], 0, 0, 0);
    }
  }
  const int grp = l >> 4;
#pragma unroll
  for (int ct = 0; ct < 2; ++ct) {
    const int ccol = ch * 32 + ct * 16 + (l & 15);
    const float bc = b[ccol];
#pragma unroll
    for (int j = 0; j < 4; ++j) {
      const int row = rbase + rt * 16 + grp * 4 + j;
      if (row < N) out[(size_t)row * 64 + ccol] = acc[ct][j] + bc;
    }
  }
}

extern "C" void kernel_launch(void* const* d_in, const int* in_sizes, int n_in,
                              void* d_out, int out_size, void* d_ws, size_t ws_size,
                              hipStream_t stream) {
  const float* feats = (const float*)d_in[0];
  const int*   src   = (const int*)d_in[1];
  const int*   dst   = (const int*)d_in[2];
  const float* W0    = (const float*)d_in[3];
  const float* b0    = (const float*)d_in[4];
  const float* g0    = (const float*)d_in[5];
  const float* be0   = (const float*)d_in[6];
  const float* W1    = (const float*)d_in[7];
  const float* b1    = (const float*)d_in[8];
  const float* g1    = (const float*)d_in[9];
  const float* be1   = (const float*)d_in[10];
  const float* W2    = (const float*)d_in[11];
  const float* b2    = (const float*)d_in[12];
  float* out = (float*)d_out;

  const int n = in_sizes[0] / 128;  // 100000
  const int e = in_sizes[1];        // 1600000
  const int NB = (n + NPB - 1) / NPB;        // 391 buckets
  const int NBLK = (e + CHUNK - 1) / CHUNK;  // 391 chunks

  float* ws = (float*)d_ws;
  auto pad4 = [](size_t x) { return (x + 3) & ~(size_t)3; };
  size_t o = 0;
  float* norm_o  = ws + o; o = pad4(o + n);
  float* norm_i  = ws + o; o = pad4(o + n);
  int*   cntD    = (int*)(ws + o); o = pad4(o + (size_t)NB * NBLK);
  int*   cntS    = (int*)(ws + o); o = pad4(o + (size_t)NB * NBLK);
  int*   offLD   = (int*)(ws + o); o = pad4(o + (size_t)NB * NBLK);
  int*   offLS   = (int*)(ws + o); o = pad4(o + (size_t)NB * NBLK);
  int*   totD    = (int*)(ws + o); o = pad4(o + NB);
  int*   totS    = (int*)(ws + o); o = pad4(o + NB);
  int*   bkt_stD = (int*)(ws + o); o = pad4(o + NB + 1);
  int*   bkt_stS = (int*)(ws + o); o = pad4(o + NB + 1);
  int*   row_st  = (int*)(ws + o); o = pad4(o + n + 1);
  unsigned int*  packedD = (unsigned int*)(ws + o);  o = pad4(o + (size_t)e);
  unsigned char* srcS    = (unsigned char*)(ws + o); o = pad4(o + (size_t)(e + 3) / 4);
  int*   edg_src = (int*)(ws + o); o = pad4(o + (size_t)e);
  unsigned short* featB = (unsigned short*)(ws + o); o = pad4(o + (size_t)n * 64);  // also hB
  unsigned short* aggB  = (unsigned short*)(ws + o); o = pad4(o + (size_t)n * 64);
  unsigned short* Wt0   = (unsigned short*)(ws + o); o = pad4(o + 128 * 128 / 2);
  unsigned short* Wt1   = (unsigned short*)(ws + o); o = pad4(o + 128 * 128 / 2);
  unsigned short* Wt2   = (unsigned short*)(ws + o); o = pad4(o + 128 * 64 / 2);
  unsigned short* hB = featB;  // featB dead after layer-0 gather

  // ---- CSR build: atomic-free radix partition ----
  passA_kernel<<<NBLK, 256, 2 * NB * sizeof(int), stream>>>(src, dst, cntD, cntS, NB, NBLK, e);
  scan1_kernel<<<2 * NB, 512, 0, stream>>>(cntD, cntS, offLD, offLS, totD, totS, NB, NBLK);
  scan2_kernel<<<1, 512, 0, stream>>>(totD, totS, bkt_stD, bkt_stS, row_st, NB, n, e);
  passB_kernel<<<NBLK, 256, 0, stream>>>(src, dst, offLD, offLS, bkt_stD, bkt_stS,
                                         packedD, srcS, NB, NBLK, e);
  passC_kernel<<<NB, 256, 0, stream>>>(packedD, bkt_stD, row_st, norm_i, edg_src, n);
  passD_kernel<<<NB, 256, 0, stream>>>(srcS, bkt_stS, norm_o, n);

  // ---- weights -> bf16 transposed; feats -> bf16 with no-fold ----
  wconv_kernel<<<(128 * 128 + 255) / 256, 256, 0, stream>>>(W0, Wt0, 128, 128);
  wconv_kernel<<<(128 * 128 + 255) / 256, 256, 0, stream>>>(W1, Wt1, 128, 128);
  wconv_kernel<<<(128 * 64 + 255) / 256, 256, 0, stream>>>(W2, Wt2, 128, 64);
  featconv_kernel<<<(n + 7) / 8, 256, 0, stream>>>(feats, norm_o, featB, n);

  const int gblocks = (n + 3) / 4;
  const int mblocks = (n + 31) / 32;

  // layer 0
  gather_agg_b<<<gblocks, 256, 0, stream>>>(featB, row_st, edg_src, norm_i, aggB, n);
  mm_mfma_ln<<<mblocks, 256, 0, stream>>>(aggB, Wt0, b0, g0, be0, norm_o, hB, n);
  // layer 1
  gather_agg_b<<<gblocks, 256, 0, stream>>>(hB, row_st, edg_src, norm_i, aggB, n);
  mm_mfma_ln<<<mblocks, 256, 0, stream>>>(aggB, Wt1, b1, g1, be1, norm_o, hB, n);
  // final layer
  gather_agg_b<<<gblocks, 256, 0, stream>>>(hB, row_st, edg_src, norm_i, aggB, n);
  mm_final_mfma<<<mblocks, 256, 0, stream>>>(aggB, Wt2, b2, out, n);
}

// Round 8
// 397.337 us; speedup vs baseline: 1.5962x; 1.0861x over previous
//
#include <hip/hip_runtime.h>

constexpr float LN_EPS = 1e-5f;

typedef __bf16 bf16x8 __attribute__((ext_vector_type(8)));
typedef float f32x4 __attribute__((ext_vector_type(4)));

__device__ __forceinline__ unsigned short f2bf(float f) {
  unsigned int u = __float_as_uint(f);
  u = (u + 0x7fffu + ((u >> 16) & 1u)) >> 16;  // RNE
  return (unsigned short)u;
}
__device__ __forceinline__ unsigned int pk2(float x, float y) {
  return (unsigned int)f2bf(x) | ((unsigned int)f2bf(y) << 16);
}
__device__ __forceinline__ float bflo(unsigned int p) { return __uint_as_float(p << 16); }
__device__ __forceinline__ float bfhi(unsigned int p) { return __uint_as_float(p & 0xffff0000u); }

#define NPB 256    // nodes per bucket (bucket = node >> 8)
#define CHUNK 4096 // edges per partition block

// ======== passA: per-chunk LDS histograms (dst-bucket & src-bucket) =======
__global__ __launch_bounds__(256) void passA_kernel(
    const int* __restrict__ src, const int* __restrict__ dst,
    int* __restrict__ cntD, int* __restrict__ cntS, int NB, int NBLK, int E) {
  extern __shared__ int sh[];  // 2*NB
  for (int j = threadIdx.x; j < 2 * NB; j += 256) sh[j] = 0;
  __syncthreads();
  const int blk = blockIdx.x;
  const int base = blk * CHUNK;
  const int end = min(base + CHUNK, E);
  for (int i = base + threadIdx.x; i < end; i += 256) {
    atomicAdd(&sh[dst[i] >> 8], 1);
    atomicAdd(&sh[NB + (src[i] >> 8)], 1);
  }
  __syncthreads();
  for (int j = threadIdx.x; j < NB; j += 256) {
    cntD[j * NBLK + blk] = sh[j];
    cntS[j * NBLK + blk] = sh[NB + j];
  }
}

// ==== scan1: per-bucket exclusive scan over blocks (grid = 2*NB blocks) ===
__global__ __launch_bounds__(512) void scan1_kernel(
    const int* __restrict__ cntD, const int* __restrict__ cntS,
    int* __restrict__ offLD, int* __restrict__ offLS,
    int* __restrict__ totD, int* __restrict__ totS, int NB, int NBLK) {
  __shared__ int p[512];
  const int t = threadIdx.x;
  const bool isS = blockIdx.x >= NB;
  const int b = isS ? blockIdx.x - NB : blockIdx.x;
  const int* cnt = isS ? cntS : cntD;
  int* offL = isS ? offLS : offLD;
  int own = (t < NBLK) ? cnt[b * NBLK + t] : 0;
  p[t] = own;
  __syncthreads();
  for (int off = 1; off < 512; off <<= 1) {
    int x = (t >= off) ? p[t - off] : 0;
    __syncthreads();
    p[t] += x;
    __syncthreads();
  }
  if (t < NBLK) offL[b * NBLK + t] = p[t] - own;
  if (t == 511) (isS ? totS : totD)[b] = p[511];
}

// ==== scan2: exclusive scan of bucket totals -> bucket_start (1 block) ====
__global__ __launch_bounds__(512) void scan2_kernel(
    const int* __restrict__ totD, const int* __restrict__ totS,
    int* __restrict__ bktD, int* __restrict__ bktS,
    int* __restrict__ row_st, int NB, int N, int E) {
  __shared__ int p[512];
  const int t = threadIdx.x;
  int own = (t < NB) ? totD[t] : 0;
  p[t] = own;
  __syncthreads();
  for (int off = 1; off < 512; off <<= 1) {
    int x = (t >= off) ? p[t - off] : 0;
    __syncthreads();
    p[t] += x;
    __syncthreads();
  }
  if (t < NB) bktD[t] = p[t] - own;
  __syncthreads();
  int own2 = (t < NB) ? totS[t] : 0;
  p[t] = own2;
  __syncthreads();
  for (int off = 1; off < 512; off <<= 1) {
    int x = (t >= off) ? p[t - off] : 0;
    __syncthreads();
    p[t] += x;
    __syncthreads();
  }
  if (t < NB) bktS[t] = p[t] - own2;
  if (t == 0) {
    bktD[NB] = E;
    bktS[NB] = E;
    row_st[N] = E;
  }
}

// ======= passB: LDS counting-sort per chunk + coalesced group copy-out ====
__global__ __launch_bounds__(256) void passB_kernel(
    const int* __restrict__ src, const int* __restrict__ dst,
    const int* __restrict__ offLD, const int* __restrict__ offLS,
    const int* __restrict__ bkt_stD, const int* __restrict__ bkt_stS,
    unsigned int* __restrict__ packedD, unsigned char* __restrict__ srcS,
    int NB, int NBLK, int E) {
  __shared__ unsigned int sD[CHUNK];
  __shared__ unsigned short bD_[CHUNK];
  __shared__ unsigned char sS_[CHUNK];
  __shared__ unsigned short bS_[CHUNK];
  __shared__ int hD[512], lD[512], hS[512], lS[512];
  const int t = threadIdx.x;
  const int blk = blockIdx.x;
  const int base = blk * CHUNK;
  const int end = min(base + CHUNK, E);
  const int cnt = end - base;
  hD[t] = 0; hD[t + 256] = 0; hS[t] = 0; hS[t + 256] = 0;
  __syncthreads();
  for (int i = base + t; i < end; i += 256) {
    atomicAdd(&hD[dst[i] >> 8], 1);
    atomicAdd(&hS[src[i] >> 8], 1);
  }
  __syncthreads();
  int oD0 = hD[t], oD1 = hD[t + 256], oS0 = hS[t], oS1 = hS[t + 256];
  for (int off = 1; off < 512; off <<= 1) {
    int xd0 = (t >= off) ? hD[t - off] : 0;
    int xd1 = (t + 256 >= off) ? hD[t + 256 - off] : 0;
    int xs0 = (t >= off) ? hS[t - off] : 0;
    int xs1 = (t + 256 >= off) ? hS[t + 256 - off] : 0;
    __syncthreads();
    hD[t] += xd0; hD[t + 256] += xd1;
    hS[t] += xs0; hS[t + 256] += xs1;
    __syncthreads();
  }
  lD[t] = hD[t] - oD0; lD[t + 256] = hD[t + 256] - oD1;
  lS[t] = hS[t] - oS0; lS[t + 256] = hS[t + 256] - oS1;
  __syncthreads();
  hD[t] = lD[t]; hD[t + 256] = lD[t + 256];
  hS[t] = lS[t]; hS[t + 256] = lS[t + 256];
  __syncthreads();
  for (int i = base + t; i < end; i += 256) {
    const int d = dst[i];
    const int s = src[i];
    const int bD = d >> 8;
    const int pD = atomicAdd(&hD[bD], 1);
    sD[pD] = ((unsigned int)(d & 255) << 24) | (unsigned int)s;
    bD_[pD] = (unsigned short)bD;
    const int bS = s >> 8;
    const int pS = atomicAdd(&hS[bS], 1);
    sS_[pS] = (unsigned char)(s & 255);
    bS_[pS] = (unsigned short)bS;
  }
  __syncthreads();
  for (int i = t; i < cnt; i += 256) {
    const int bD = bD_[i];
    packedD[bkt_stD[bD] + offLD[bD * NBLK + blk] + (i - lD[bD])] = sD[i];
    const int bS = bS_[i];
    srcS[bkt_stS[bS] + offLS[bS * NBLK + blk] + (i - lS[bS])] = sS_[i];
  }
}

// ===== passC: per-bucket local CSR (row_st, norm_i, sorted edge_src) ======
__global__ __launch_bounds__(256) void passC_kernel(
    const unsigned int* __restrict__ packed, const int* __restrict__ bucket_start,
    int* __restrict__ row_st, float* __restrict__ ni,
    int* __restrict__ edge_src, int N) {
  __shared__ int cnt[NPB];
  __shared__ int cur[NPB];
  __shared__ int tmp[NPB];
  const int b = blockIdx.x;
  const int t = threadIdx.x;
  const int v0 = b * NPB;
  const int bs = bucket_start[b];
  const int be = bucket_start[b + 1];
  cnt[t] = 0;
  __syncthreads();
  for (int i = bs + t; i < be; i += 256)
    atomicAdd(&cnt[packed[i] >> 24], 1);
  __syncthreads();
  int own = cnt[t];
  tmp[t] = own;
  __syncthreads();
  for (int off = 1; off < NPB; off <<= 1) {
    int x = (t >= off) ? tmp[t - off] : 0;
    __syncthreads();
    tmp[t] += x;
    __syncthreads();
  }
  const int pref = tmp[t] - own;
  if (v0 + t < N) {
    row_st[v0 + t] = bs + pref;
    ni[v0 + t] = rsqrtf(fmaxf((float)own, 1.0f));
  }
  cur[t] = bs + pref;
  __syncthreads();
  for (int i = bs + t; i < be; i += 256) {
    unsigned int p = packed[i];
    int pos = atomicAdd(&cur[p >> 24], 1);
    edge_src[pos] = (int)(p & 0xFFFFFFu);
  }
}

// ========= passD: per-src-bucket count -> norm_o (no global atomics) ======
__global__ __launch_bounds__(256) void passD_kernel(
    const unsigned char* __restrict__ srcS, const int* __restrict__ bkt_stS,
    float* __restrict__ no, int N) {
  __shared__ int cnt[NPB];
  const int b = blockIdx.x;
  const int t = threadIdx.x;
  cnt[t] = 0;
  __syncthreads();
  const int bs = bkt_stS[b];
  const int be = bkt_stS[b + 1];
  for (int i = bs + t; i < be; i += 256)
    atomicAdd(&cnt[srcS[i]], 1);
  __syncthreads();
  const int v = b * NPB + t;
  if (v < N) no[v] = rsqrtf(fmaxf((float)cnt[t], 1.0f));
}

// ===================== weight transpose + bf16 convert ====================
__global__ void wconv_kernel(const float* __restrict__ W, unsigned short* __restrict__ Wt,
                             int K, int C) {
  int i = blockIdx.x * blockDim.x + threadIdx.x;
  if (i < K * C) {
    int k = i / C, c = i - k * C;
    Wt[c * K + k] = f2bf(W[i]);
  }
}

// ============= feats f32 -> bf16 with norm_o fold: out = no[r]*F[r][c] ====
__global__ __launch_bounds__(256) void featconv_kernel(const float* __restrict__ F,
                                                       const float* __restrict__ no,
                                                       unsigned short* __restrict__ out, int N) {
  int row = blockIdx.x * 8 + (threadIdx.x >> 5);
  if (row >= N) return;
  int c = (threadIdx.x & 31) * 4;
  float4 v = *reinterpret_cast<const float4*>(F + (size_t)row * 128 + c);
  float nof = no[row];
  uint2 p = {pk2(v.x * nof, v.y * nof), pk2(v.z * nof, v.w * nof)};
  *reinterpret_cast<uint2*>(out + (size_t)row * 128 + c) = p;
}

// ============== gather aggregation, 128-wide, 2 rows/wave-load ============
// Wave = 2 half-waves: half 0 takes even edges, half 1 odd. lane covers 4
// cols (uint2 = 8B). Cross-half combine via shfl_xor(32) at the end.
__global__ __launch_bounds__(256) void gather_agg_b(
    const unsigned short* __restrict__ hB, const int* __restrict__ row_start,
    const int* __restrict__ edge_src, const float* __restrict__ ni,
    unsigned short* __restrict__ aggB, int N) {
  const int v = blockIdx.x * 4 + (threadIdx.x >> 6);
  if (v >= N) return;
  const int l = threadIdx.x & 63;
  const int half = l >> 5;
  const int lane = l & 31;
  const int s = row_start[v];
  const int e = row_start[v + 1];
  const int co = 4 * lane;
  float a0 = 0, a1 = 0, a2 = 0, a3 = 0;
  float b0 = 0, b1 = 0, b2 = 0, b3 = 0;
  float c0 = 0, c1 = 0, c2 = 0, c3 = 0;
  float d0 = 0, d1 = 0, d2 = 0, d3 = 0;
  int j = s;
  for (; j + 8 <= e; j += 8) {
    int u0 = edge_src[j + half];
    int u1 = edge_src[j + 2 + half];
    int u2 = edge_src[j + 4 + half];
    int u3 = edge_src[j + 6 + half];
    uint2 p0 = *reinterpret_cast<const uint2*>(hB + (size_t)u0 * 128 + co);
    uint2 p1 = *reinterpret_cast<const uint2*>(hB + (size_t)u1 * 128 + co);
    uint2 p2 = *reinterpret_cast<const uint2*>(hB + (size_t)u2 * 128 + co);
    uint2 p3 = *reinterpret_cast<const uint2*>(hB + (size_t)u3 * 128 + co);
    a0 += bflo(p0.x); a1 += bfhi(p0.x); a2 += bflo(p0.y); a3 += bfhi(p0.y);
    b0 += bflo(p1.x); b1 += bfhi(p1.x); b2 += bflo(p1.y); b3 += bfhi(p1.y);
    c0 += bflo(p2.x); c1 += bfhi(p2.x); c2 += bflo(p2.y); c3 += bfhi(p2.y);
    d0 += bflo(p3.x); d1 += bfhi(p3.x); d2 += bflo(p3.y); d3 += bfhi(p3.y);
  }
  for (; j + 2 <= e; j += 2) {
    int u0 = edge_src[j + half];
    uint2 p0 = *reinterpret_cast<const uint2*>(hB + (size_t)u0 * 128 + co);
    a0 += bflo(p0.x); a1 += bfhi(p0.x); a2 += bflo(p0.y); a3 += bfhi(p0.y);
  }
  if (j < e && half == 0) {
    int u0 = edge_src[j];
    uint2 p0 = *reinterpret_cast<const uint2*>(hB + (size_t)u0 * 128 + co);
    a0 += bflo(p0.x); a1 += bfhi(p0.x); a2 += bflo(p0.y); a3 += bfhi(p0.y);
  }
  a0 = (a0 + b0) + (c0 + d0);
  a1 = (a1 + b1) + (c1 + d1);
  a2 = (a2 + b2) + (c2 + d2);
  a3 = (a3 + b3) + (c3 + d3);
  a0 += __shfl_xor(a0, 32);
  a1 += __shfl_xor(a1, 32);
  a2 += __shfl_xor(a2, 32);
  a3 += __shfl_xor(a3, 32);
  if (half == 0) {
    const float niv = ni[v];
    uint2 po = {pk2(a0 * niv, a1 * niv), pk2(a2 * niv, a3 * niv)};
    *reinterpret_cast<uint2*>(aggB + (size_t)v * 128 + co) = po;
  }
}

// ====== final gather, 64-wide: out[v] = ni[v]*sum z[u] + b2  (f32 out) ====
__global__ __launch_bounds__(256) void gather_out(
    const unsigned short* __restrict__ zB, const int* __restrict__ row_start,
    const int* __restrict__ edge_src, const float* __restrict__ ni,
    const float* __restrict__ bias, float* __restrict__ out, int N) {
  const int v = blockIdx.x * 4 + (threadIdx.x >> 6);
  if (v >= N) return;
  const int l = threadIdx.x & 63;
  const int half = l >> 5;
  const int lane = l & 31;
  const int s = row_start[v];
  const int e = row_start[v + 1];
  const int co = 2 * lane;
  float a0 = 0, a1 = 0, b0 = 0, b1 = 0, c0 = 0, c1 = 0, d0 = 0, d1 = 0;
  int j = s;
  for (; j + 8 <= e; j += 8) {
    int u0 = edge_src[j + half];
    int u1 = edge_src[j + 2 + half];
    int u2 = edge_src[j + 4 + half];
    int u3 = edge_src[j + 6 + half];
    unsigned int p0 = *reinterpret_cast<const unsigned int*>(zB + (size_t)u0 * 64 + co);
    unsigned int p1 = *reinterpret_cast<const unsigned int*>(zB + (size_t)u1 * 64 + co);
    unsigned int p2 = *reinterpret_cast<const unsigned int*>(zB + (size_t)u2 * 64 + co);
    unsigned int p3 = *reinterpret_cast<const unsigned int*>(zB + (size_t)u3 * 64 + co);
    a0 += bflo(p0); a1 += bfhi(p0);
    b0 += bflo(p1); b1 += bfhi(p1);
    c0 += bflo(p2); c1 += bfhi(p2);
    d0 += bflo(p3); d1 += bfhi(p3);
  }
  for (; j + 2 <= e; j += 2) {
    int u0 = edge_src[j + half];
    unsigned int p0 = *reinterpret_cast<const unsigned int*>(zB + (size_t)u0 * 64 + co);
    a0 += bflo(p0); a1 += bfhi(p0);
  }
  if (j < e && half == 0) {
    int u0 = edge_src[j];
    unsigned int p0 = *reinterpret_cast<const unsigned int*>(zB + (size_t)u0 * 64 + co);
    a0 += bflo(p0); a1 += bfhi(p0);
  }
  a0 = (a0 + b0) + (c0 + d0);
  a1 = (a1 + b1) + (c1 + d1);
  a0 += __shfl_xor(a0, 32);
  a1 += __shfl_xor(a1, 32);
  if (half == 0) {
    const float niv = ni[v];
    float2 bb = *reinterpret_cast<const float2*>(bias + co);
    float2 w = {a0 * niv + bb.x, a1 * niv + bb.y};
    *reinterpret_cast<float2*>(out + (size_t)v * 64 + co) = w;
  }
}

// ====== MFMA matmul [N,128]x[128,128] + bias + LN + ReLU + no-fold ========
__global__ __launch_bounds__(256) void mm_mfma_ln(
    const unsigned short* __restrict__ A, const unsigned short* __restrict__ Wt,
    const float* __restrict__ b, const float* __restrict__ g,
    const float* __restrict__ be, const float* __restrict__ no,
    unsigned short* __restrict__ out, int N) {
  __shared__ float sS[2][2][16];
  __shared__ float sQ[2][2][16];
  __shared__ float sNo[32];
  const int rbase = blockIdx.x * 32;
  const int w = threadIdx.x >> 6;
  const int l = threadIdx.x & 63;
  const int rt = w & 1, ch = w >> 1;
  if (threadIdx.x < 32) sNo[threadIdx.x] = no[min(rbase + (int)threadIdx.x, N - 1)];
  const int arow = min(rbase + rt * 16 + (l & 15), N - 1);
  const int kof = (l >> 4) * 8;

  bf16x8 af[4];
  const unsigned short* ap = A + (size_t)arow * 128 + kof;
#pragma unroll
  for (int kk = 0; kk < 4; ++kk)
    af[kk] = *reinterpret_cast<const bf16x8*>(ap + kk * 32);

  f32x4 acc[4] = {};
#pragma unroll
  for (int ct = 0; ct < 4; ++ct) {
    const int ccol = ch * 64 + ct * 16 + (l & 15);
    const unsigned short* bp = Wt + (size_t)ccol * 128 + kof;
#pragma unroll
    for (int kk = 0; kk < 4; ++kk) {
      bf16x8 bfr = *reinterpret_cast<const bf16x8*>(bp + kk * 32);
      acc[ct] = __builtin_amdgcn_mfma_f32_16x16x32_bf16(af[kk], bfr, acc[ct], 0, 0, 0);
    }
  }

  float s[4] = {0.f, 0.f, 0.f, 0.f}, q[4] = {0.f, 0.f, 0.f, 0.f};
#pragma unroll
  for (int ct = 0; ct < 4; ++ct) {
    const float bc = b[ch * 64 + ct * 16 + (l & 15)];
#pragma unroll
    for (int j = 0; j < 4; ++j) {
      float v = acc[ct][j] + bc;
      acc[ct][j] = v;
      s[j] += v;
      q[j] += v * v;
    }
  }
#pragma unroll
  for (int j = 0; j < 4; ++j) {
#pragma unroll
    for (int off = 1; off < 16; off <<= 1) {
      s[j] += __shfl_xor(s[j], off);
      q[j] += __shfl_xor(q[j], off);
    }
  }
  const int grp = l >> 4;
  if ((l & 15) == 0) {
#pragma unroll
    for (int j = 0; j < 4; ++j) {
      sS[rt][ch][grp * 4 + j] = s[j];
      sQ[rt][ch][grp * 4 + j] = q[j];
    }
  }
  __syncthreads();

#pragma unroll
  for (int j = 0; j < 4; ++j) {
    const int r = grp * 4 + j;
    const int row = rbase + rt * 16 + r;
    float S = sS[rt][0][r] + sS[rt][1][r];
    float Q = sQ[rt][0][r] + sQ[rt][1][r];
    float mu = S * (1.f / 128.f);
    float rstd = rsqrtf(fmaxf(Q * (1.f / 128.f) - mu * mu, 0.f) + LN_EPS);
    float nof = sNo[rt * 16 + r];
    if (row < N) {
#pragma unroll
      for (int ct = 0; ct < 4; ++ct) {
        const int ccol = ch * 64 + ct * 16 + (l & 15);
        float y = (acc[ct][j] - mu) * rstd * g[ccol] + be[ccol];
        y = fmaxf(y, 0.f) * nof;
        out[(size_t)row * 128 + ccol] = f2bf(y);
      }
    }
  }
}

// ====== z = hB @ W2 -> bf16 [N,64], NO bias (commuted final layer) ========
__global__ __launch_bounds__(256) void mm_z_mfma(
    const unsigned short* __restrict__ A, const unsigned short* __restrict__ Wt,
    unsigned short* __restrict__ zB, int N) {
  const int rbase = blockIdx.x * 32;
  const int w = threadIdx.x >> 6;
  const int l = threadIdx.x & 63;
  const int rt = w & 1, ch = w >> 1;
  const int arow = min(rbase + rt * 16 + (l & 15), N - 1);
  const int kof = (l >> 4) * 8;

  bf16x8 af[4];
  const unsigned short* ap = A + (size_t)arow * 128 + kof;
#pragma unroll
  for (int kk = 0; kk < 4; ++kk)
    af[kk] = *reinterpret_cast<const bf16x8*>(ap + kk * 32);

  f32x4 acc[2] = {};
#pragma unroll
  for (int ct = 0; ct < 2; ++ct) {
    const int ccol = ch * 32 + ct * 16 + (l & 15);
    const unsigned short* bp = Wt + (size_t)ccol * 128 + kof;
#pragma unroll
    for (int kk = 0; kk < 4; ++kk) {
      bf16x8 bfr = *reinterpret_cast<const bf16x8*>(bp + kk * 32);
      acc[ct] = __builtin_amdgcn_mfma_f32_16x16x32_bf16(af[kk], bfr, acc[ct], 0, 0, 0);
    }
  }
  const int grp = l >> 4;
#pragma unroll
  for (int ct = 0; ct < 2; ++ct) {
    const int ccol = ch * 32 + ct * 16 + (l & 15);
#pragma unroll
    for (int j = 0; j < 4; ++j) {
      const int row = rbase + rt * 16 + grp * 4 + j;
      if (row < N) zB[(size_t)row * 64 + ccol] = f2bf(acc[ct][j]);
    }
  }
}

extern "C" void kernel_launch(void* const* d_in, const int* in_sizes, int n_in,
                              void* d_out, int out_size, void* d_ws, size_t ws_size,
                              hipStream_t stream) {
  const float* feats = (const float*)d_in[0];
  const int*   src   = (const int*)d_in[1];
  const int*   dst   = (const int*)d_in[2];
  const float* W0    = (const float*)d_in[3];
  const float* b0    = (const float*)d_in[4];
  const float* g0    = (const float*)d_in[5];
  const float* be0   = (const float*)d_in[6];
  const float* W1    = (const float*)d_in[7];
  const float* b1    = (const float*)d_in[8];
  const float* g1    = (const float*)d_in[9];
  const float* be1   = (const float*)d_in[10];
  const float* W2    = (const float*)d_in[11];
  const float* b2    = (const float*)d_in[12];
  float* out = (float*)d_out;

  const int n = in_sizes[0] / 128;  // 100000
  const int e = in_sizes[1];        // 1600000
  const int NB = (n + NPB - 1) / NPB;        // 391 buckets
  const int NBLK = (e + CHUNK - 1) / CHUNK;  // 391 chunks

  float* ws = (float*)d_ws;
  auto pad4 = [](size_t x) { return (x + 3) & ~(size_t)3; };
  size_t o = 0;
  float* norm_o  = ws + o; o = pad4(o + n);
  float* norm_i  = ws + o; o = pad4(o + n);
  int*   cntD    = (int*)(ws + o); o = pad4(o + (size_t)NB * NBLK);
  int*   cntS    = (int*)(ws + o); o = pad4(o + (size_t)NB * NBLK);
  int*   offLD   = (int*)(ws + o); o = pad4(o + (size_t)NB * NBLK);
  int*   offLS   = (int*)(ws + o); o = pad4(o + (size_t)NB * NBLK);
  int*   totD    = (int*)(ws + o); o = pad4(o + NB);
  int*   totS    = (int*)(ws + o); o = pad4(o + NB);
  int*   bkt_stD = (int*)(ws + o); o = pad4(o + NB + 1);
  int*   bkt_stS = (int*)(ws + o); o = pad4(o + NB + 1);
  int*   row_st  = (int*)(ws + o); o = pad4(o + n + 1);
  unsigned int*  packedD = (unsigned int*)(ws + o);  o = pad4(o + (size_t)e);
  unsigned char* srcS    = (unsigned char*)(ws + o); o = pad4(o + (size_t)(e + 3) / 4);
  int*   edg_src = (int*)(ws + o); o = pad4(o + (size_t)e);
  unsigned short* featB = (unsigned short*)(ws + o); o = pad4(o + (size_t)n * 64);  // also hB
  unsigned short* aggB  = (unsigned short*)(ws + o); o = pad4(o + (size_t)n * 64);  // also zB
  unsigned short* Wt0   = (unsigned short*)(ws + o); o = pad4(o + 128 * 128 / 2);
  unsigned short* Wt1   = (unsigned short*)(ws + o); o = pad4(o + 128 * 128 / 2);
  unsigned short* Wt2   = (unsigned short*)(ws + o); o = pad4(o + 128 * 64 / 2);
  unsigned short* hB = featB;  // featB dead after layer-0 gather
  unsigned short* zB = aggB;   // aggB dead after layer-1 mm

  // ---- CSR build: atomic-free radix partition ----
  passA_kernel<<<NBLK, 256, 2 * NB * sizeof(int), stream>>>(src, dst, cntD, cntS, NB, NBLK, e);
  scan1_kernel<<<2 * NB, 512, 0, stream>>>(cntD, cntS, offLD, offLS, totD, totS, NB, NBLK);
  scan2_kernel<<<1, 512, 0, stream>>>(totD, totS, bkt_stD, bkt_stS, row_st, NB, n, e);
  passB_kernel<<<NBLK, 256, 0, stream>>>(src, dst, offLD, offLS, bkt_stD, bkt_stS,
                                         packedD, srcS, NB, NBLK, e);
  passC_kernel<<<NB, 256, 0, stream>>>(packedD, bkt_stD, row_st, norm_i, edg_src, n);
  passD_kernel<<<NB, 256, 0, stream>>>(srcS, bkt_stS, norm_o, n);

  // ---- weights -> bf16 transposed; feats -> bf16 with no-fold ----
  wconv_kernel<<<(128 * 128 + 255) / 256, 256, 0, stream>>>(W0, Wt0, 128, 128);
  wconv_kernel<<<(128 * 128 + 255) / 256, 256, 0, stream>>>(W1, Wt1, 128, 128);
  wconv_kernel<<<(128 * 64 + 255) / 256, 256, 0, stream>>>(W2, Wt2, 128, 64);
  featconv_kernel<<<(n + 7) / 8, 256, 0, stream>>>(feats, norm_o, featB, n);

  const int gblocks = (n + 3) / 4;
  const int mblocks = (n + 31) / 32;

  // layer 0
  gather_agg_b<<<gblocks, 256, 0, stream>>>(featB, row_st, edg_src, norm_i, aggB, n);
  mm_mfma_ln<<<mblocks, 256, 0, stream>>>(aggB, Wt0, b0, g0, be0, norm_o, hB, n);
  // layer 1
  gather_agg_b<<<gblocks, 256, 0, stream>>>(hB, row_st, edg_src, norm_i, aggB, n);
  mm_mfma_ln<<<mblocks, 256, 0, stream>>>(aggB, Wt1, b1, g1, be1, norm_o, hB, n);
  // final layer (commuted): z = hB@W2, then 64-wide gather + bias -> out
  mm_z_mfma<<<mblocks, 256, 0, stream>>>(hB, Wt2, zB, n);
  gather_out<<<gblocks, 256, 0, stream>>>(zB, row_st, edg_src, norm_i, b2, out, n);
}

// Round 9
// 388.938 us; speedup vs baseline: 1.6307x; 1.0216x over previous
//
#include <hip/hip_runtime.h>
#include <hip/hip_fp16.h>

constexpr float LN_EPS = 1e-5f;

typedef _Float16 f16x8 __attribute__((ext_vector_type(8)));
typedef float f32x4 __attribute__((ext_vector_type(4)));

__device__ __forceinline__ unsigned short f2h(float f) {
  return __half_as_ushort(__float2half_rn(f));
}
__device__ __forceinline__ unsigned int pk2h(float x, float y) {
  return (unsigned int)f2h(x) | ((unsigned int)f2h(y) << 16);
}
__device__ __forceinline__ __half2 u2h2(unsigned int u) {
  return *reinterpret_cast<__half2*>(&u);
}

#define NPB 256    // nodes per bucket (bucket = node >> 8)
#define CHUNK 4096 // edges per partition block

// ======== passA: per-chunk LDS histograms (dst-bucket & src-bucket) =======
__global__ __launch_bounds__(256) void passA_kernel(
    const int* __restrict__ src, const int* __restrict__ dst,
    int* __restrict__ cntD, int* __restrict__ cntS, int NB, int NBLK, int E) {
  extern __shared__ int sh[];  // 2*NB
  for (int j = threadIdx.x; j < 2 * NB; j += 256) sh[j] = 0;
  __syncthreads();
  const int blk = blockIdx.x;
  const int base = blk * CHUNK;
  const int end = min(base + CHUNK, E);
  const int cnt = end - base;
  const int nv = cnt >> 2;  // base is 16B-aligned (CHUNK%4==0)
  const int4* d4p = reinterpret_cast<const int4*>(dst + base);
  const int4* s4p = reinterpret_cast<const int4*>(src + base);
  for (int q = threadIdx.x; q < nv; q += 256) {
    int4 d4 = d4p[q];
    int4 s4 = s4p[q];
    atomicAdd(&sh[d4.x >> 8], 1); atomicAdd(&sh[d4.y >> 8], 1);
    atomicAdd(&sh[d4.z >> 8], 1); atomicAdd(&sh[d4.w >> 8], 1);
    atomicAdd(&sh[NB + (s4.x >> 8)], 1); atomicAdd(&sh[NB + (s4.y >> 8)], 1);
    atomicAdd(&sh[NB + (s4.z >> 8)], 1); atomicAdd(&sh[NB + (s4.w >> 8)], 1);
  }
  for (int i = (nv << 2) + threadIdx.x; i < cnt; i += 256) {
    atomicAdd(&sh[dst[base + i] >> 8], 1);
    atomicAdd(&sh[NB + (src[base + i] >> 8)], 1);
  }
  __syncthreads();
  for (int j = threadIdx.x; j < NB; j += 256) {
    cntD[j * NBLK + blk] = sh[j];
    cntS[j * NBLK + blk] = sh[NB + j];
  }
}

// ==== scan1: per-bucket exclusive scan over blocks (grid = 2*NB blocks) ===
__global__ __launch_bounds__(512) void scan1_kernel(
    const int* __restrict__ cntD, const int* __restrict__ cntS,
    int* __restrict__ offLD, int* __restrict__ offLS,
    int* __restrict__ totD, int* __restrict__ totS, int NB, int NBLK) {
  __shared__ int p[512];
  const int t = threadIdx.x;
  const bool isS = blockIdx.x >= NB;
  const int b = isS ? blockIdx.x - NB : blockIdx.x;
  const int* cnt = isS ? cntS : cntD;
  int* offL = isS ? offLS : offLD;
  int own = (t < NBLK) ? cnt[b * NBLK + t] : 0;
  p[t] = own;
  __syncthreads();
  for (int off = 1; off < 512; off <<= 1) {
    int x = (t >= off) ? p[t - off] : 0;
    __syncthreads();
    p[t] += x;
    __syncthreads();
  }
  if (t < NBLK) offL[b * NBLK + t] = p[t] - own;
  if (t == 511) (isS ? totS : totD)[b] = p[511];
}

// ==== scan2: exclusive scan of bucket totals -> bucket_start (1 block) ====
__global__ __launch_bounds__(512) void scan2_kernel(
    const int* __restrict__ totD, const int* __restrict__ totS,
    int* __restrict__ bktD, int* __restrict__ bktS,
    int* __restrict__ row_st, int NB, int N, int E) {
  __shared__ int p[512];
  const int t = threadIdx.x;
  int own = (t < NB) ? totD[t] : 0;
  p[t] = own;
  __syncthreads();
  for (int off = 1; off < 512; off <<= 1) {
    int x = (t >= off) ? p[t - off] : 0;
    __syncthreads();
    p[t] += x;
    __syncthreads();
  }
  if (t < NB) bktD[t] = p[t] - own;
  __syncthreads();
  int own2 = (t < NB) ? totS[t] : 0;
  p[t] = own2;
  __syncthreads();
  for (int off = 1; off < 512; off <<= 1) {
    int x = (t >= off) ? p[t - off] : 0;
    __syncthreads();
    p[t] += x;
    __syncthreads();
  }
  if (t < NB) bktS[t] = p[t] - own2;
  if (t == 0) {
    bktD[NB] = E;
    bktS[NB] = E;
    row_st[N] = E;
  }
}

// ===== passB: reuse passA histograms; single edge read; LDS sort+copyout ==
__global__ __launch_bounds__(256) void passB_kernel(
    const int* __restrict__ src, const int* __restrict__ dst,
    const int* __restrict__ cntD, const int* __restrict__ cntS,
    const int* __restrict__ offLD, const int* __restrict__ offLS,
    const int* __restrict__ bkt_stD, const int* __restrict__ bkt_stS,
    unsigned int* __restrict__ packedD, unsigned char* __restrict__ srcS,
    int NB, int NBLK, int E) {
  __shared__ unsigned int sD[CHUNK];
  __shared__ unsigned short bD_[CHUNK];
  __shared__ unsigned char sS_[CHUNK];
  __shared__ unsigned short bS_[CHUNK];
  __shared__ int hD[512], lD[512], hS[512], lS[512];
  const int t = threadIdx.x;
  const int blk = blockIdx.x;
  const int base = blk * CHUNK;
  const int end = min(base + CHUNK, E);
  const int cnt = end - base;
  // load this chunk's histograms (computed by passA)
  hD[t] = (t < NB) ? cntD[t * NBLK + blk] : 0;
  hD[t + 256] = (t + 256 < NB) ? cntD[(t + 256) * NBLK + blk] : 0;
  hS[t] = (t < NB) ? cntS[t * NBLK + blk] : 0;
  hS[t + 256] = (t + 256 < NB) ? cntS[(t + 256) * NBLK + blk] : 0;
  __syncthreads();
  int oD0 = hD[t], oD1 = hD[t + 256], oS0 = hS[t], oS1 = hS[t + 256];
  for (int off = 1; off < 512; off <<= 1) {
    int xd0 = (t >= off) ? hD[t - off] : 0;
    int xd1 = (t + 256 >= off) ? hD[t + 256 - off] : 0;
    int xs0 = (t >= off) ? hS[t - off] : 0;
    int xs1 = (t + 256 >= off) ? hS[t + 256 - off] : 0;
    __syncthreads();
    hD[t] += xd0; hD[t + 256] += xd1;
    hS[t] += xs0; hS[t + 256] += xs1;
    __syncthreads();
  }
  lD[t] = hD[t] - oD0; lD[t + 256] = hD[t + 256] - oD1;
  lS[t] = hS[t] - oS0; lS[t + 256] = hS[t + 256] - oS1;
  __syncthreads();
  hD[t] = lD[t]; hD[t + 256] = lD[t + 256];
  hS[t] = lS[t]; hS[t + 256] = lS[t + 256];
  __syncthreads();
  // single vectorized edge read + LDS scatter
  const int nv = cnt >> 2;
  const int4* d4p = reinterpret_cast<const int4*>(dst + base);
  const int4* s4p = reinterpret_cast<const int4*>(src + base);
  for (int q = t; q < nv; q += 256) {
    int4 d4 = d4p[q];
    int4 s4 = s4p[q];
#pragma unroll
    for (int k = 0; k < 4; ++k) {
      const int d = (&d4.x)[k];
      const int s = (&s4.x)[k];
      const int bD = d >> 8;
      const int pD = atomicAdd(&hD[bD], 1);
      sD[pD] = ((unsigned int)(d & 255) << 24) | (unsigned int)s;
      bD_[pD] = (unsigned short)bD;
      const int bS = s >> 8;
      const int pS = atomicAdd(&hS[bS], 1);
      sS_[pS] = (unsigned char)(s & 255);
      bS_[pS] = (unsigned short)bS;
    }
  }
  for (int i = (nv << 2) + t; i < cnt; i += 256) {
    const int d = dst[base + i];
    const int s = src[base + i];
    const int bD = d >> 8;
    const int pD = atomicAdd(&hD[bD], 1);
    sD[pD] = ((unsigned int)(d & 255) << 24) | (unsigned int)s;
    bD_[pD] = (unsigned short)bD;
    const int bS = s >> 8;
    const int pS = atomicAdd(&hS[bS], 1);
    sS_[pS] = (unsigned char)(s & 255);
    bS_[pS] = (unsigned short)bS;
  }
  __syncthreads();
  for (int i = t; i < cnt; i += 256) {
    const int bD = bD_[i];
    packedD[bkt_stD[bD] + offLD[bD * NBLK + blk] + (i - lD[bD])] = sD[i];
    const int bS = bS_[i];
    srcS[bkt_stS[bS] + offLS[bS * NBLK + blk] + (i - lS[bS])] = sS_[i];
  }
}

// ===== passC: per-bucket local CSR (row_st, norm_i, sorted edge_src) ======
__global__ __launch_bounds__(256) void passC_kernel(
    const unsigned int* __restrict__ packed, const int* __restrict__ bucket_start,
    int* __restrict__ row_st, float* __restrict__ ni,
    int* __restrict__ edge_src, int N) {
  __shared__ int cnt[NPB];
  __shared__ int cur[NPB];
  __shared__ int tmp[NPB];
  const int b = blockIdx.x;
  const int t = threadIdx.x;
  const int v0 = b * NPB;
  const int bs = bucket_start[b];
  const int be = bucket_start[b + 1];
  cnt[t] = 0;
  __syncthreads();
  // vectorized histogram with alignment handling
  const int a0 = bs + ((4 - (bs & 3)) & 3);
  const int a1 = a0 + (((be - a0) >> 2) << 2);
  for (int i = bs + t; i < min(a0, be); i += 256)
    atomicAdd(&cnt[packed[i] >> 24], 1);
  const uint4* p4 = reinterpret_cast<const uint4*>(packed + a0);
  const int nv = (a1 - a0) >> 2;
  for (int q = t; q < nv; q += 256) {
    uint4 p = p4[q];
    atomicAdd(&cnt[p.x >> 24], 1); atomicAdd(&cnt[p.y >> 24], 1);
    atomicAdd(&cnt[p.z >> 24], 1); atomicAdd(&cnt[p.w >> 24], 1);
  }
  for (int i = max(a1, bs) + t; i < be; i += 256)
    atomicAdd(&cnt[packed[i] >> 24], 1);
  __syncthreads();
  int own = cnt[t];
  tmp[t] = own;
  __syncthreads();
  for (int off = 1; off < NPB; off <<= 1) {
    int x = (t >= off) ? tmp[t - off] : 0;
    __syncthreads();
    tmp[t] += x;
    __syncthreads();
  }
  const int pref = tmp[t] - own;
  if (v0 + t < N) {
    row_st[v0 + t] = bs + pref;
    ni[v0 + t] = rsqrtf(fmaxf((float)own, 1.0f));
  }
  cur[t] = bs + pref;
  __syncthreads();
  for (int i = bs + t; i < min(a0, be); i += 256) {
    unsigned int p = packed[i];
    int pos = atomicAdd(&cur[p >> 24], 1);
    edge_src[pos] = (int)(p & 0xFFFFFFu);
  }
  for (int q = t; q < nv; q += 256) {
    uint4 p = p4[q];
#pragma unroll
    for (int k = 0; k < 4; ++k) {
      unsigned int pv = (&p.x)[k];
      int pos = atomicAdd(&cur[pv >> 24], 1);
      edge_src[pos] = (int)(pv & 0xFFFFFFu);
    }
  }
  for (int i = max(a1, bs) + t; i < be; i += 256) {
    unsigned int p = packed[i];
    int pos = atomicAdd(&cur[p >> 24], 1);
    edge_src[pos] = (int)(p & 0xFFFFFFu);
  }
}

// ========= passD: per-src-bucket count -> norm_o (no global atomics) ======
__global__ __launch_bounds__(256) void passD_kernel(
    const unsigned char* __restrict__ srcS, const int* __restrict__ bkt_stS,
    float* __restrict__ no, int N) {
  __shared__ int cnt[NPB];
  const int b = blockIdx.x;
  const int t = threadIdx.x;
  cnt[t] = 0;
  __syncthreads();
  const int bs = bkt_stS[b];
  const int be = bkt_stS[b + 1];
  for (int i = bs + t; i < be; i += 256)
    atomicAdd(&cnt[srcS[i]], 1);
  __syncthreads();
  const int v = b * NPB + t;
  if (v < N) no[v] = rsqrtf(fmaxf((float)cnt[t], 1.0f));
}

// ===================== weight transpose + f16 convert =====================
__global__ void wconv_kernel(const float* __restrict__ W, unsigned short* __restrict__ Wt,
                             int K, int C) {
  int i = blockIdx.x * blockDim.x + threadIdx.x;
  if (i < K * C) {
    int k = i / C, c = i - k * C;
    Wt[c * K + k] = f2h(W[i]);
  }
}

// ============= feats f32 -> f16 with norm_o fold: out = no[r]*F[r][c] =====
__global__ __launch_bounds__(256) void featconv_kernel(const float* __restrict__ F,
                                                       const float* __restrict__ no,
                                                       unsigned short* __restrict__ out, int N) {
  int row = blockIdx.x * 8 + (threadIdx.x >> 5);
  if (row >= N) return;
  int c = (threadIdx.x & 31) * 4;
  float4 v = *reinterpret_cast<const float4*>(F + (size_t)row * 128 + c);
  float nof = no[row];
  uint2 p = {pk2h(v.x * nof, v.y * nof), pk2h(v.z * nof, v.w * nof)};
  *reinterpret_cast<uint2*>(out + (size_t)row * 128 + c) = p;
}

// ============== gather aggregation, 128-wide, fp16 packed adds ============
__global__ __launch_bounds__(256) void gather_agg_h(
    const unsigned short* __restrict__ hH, const int* __restrict__ row_start,
    const int* __restrict__ edge_src, const float* __restrict__ ni,
    unsigned short* __restrict__ aggH, int N) {
  const int v = blockIdx.x * 4 + (threadIdx.x >> 6);
  if (v >= N) return;
  const int l = threadIdx.x & 63;
  const int half = l >> 5;
  const int lane = l & 31;
  const int s = row_start[v];
  const int e = row_start[v + 1];
  const int co = 4 * lane;
  const __half2 z = __float2half2_rn(0.f);
  __half2 A0 = z, A1 = z, B0 = z, B1 = z, C0 = z, C1 = z, D0 = z, D1 = z;
  int j = s;
  for (; j + 8 <= e; j += 8) {
    int u0 = edge_src[j + half];
    int u1 = edge_src[j + 2 + half];
    int u2 = edge_src[j + 4 + half];
    int u3 = edge_src[j + 6 + half];
    uint2 p0 = *reinterpret_cast<const uint2*>(hH + (size_t)u0 * 128 + co);
    uint2 p1 = *reinterpret_cast<const uint2*>(hH + (size_t)u1 * 128 + co);
    uint2 p2 = *reinterpret_cast<const uint2*>(hH + (size_t)u2 * 128 + co);
    uint2 p3 = *reinterpret_cast<const uint2*>(hH + (size_t)u3 * 128 + co);
    A0 = __hadd2(A0, u2h2(p0.x)); A1 = __hadd2(A1, u2h2(p0.y));
    B0 = __hadd2(B0, u2h2(p1.x)); B1 = __hadd2(B1, u2h2(p1.y));
    C0 = __hadd2(C0, u2h2(p2.x)); C1 = __hadd2(C1, u2h2(p2.y));
    D0 = __hadd2(D0, u2h2(p3.x)); D1 = __hadd2(D1, u2h2(p3.y));
  }
  for (; j + 2 <= e; j += 2) {
    int u0 = edge_src[j + half];
    uint2 p0 = *reinterpret_cast<const uint2*>(hH + (size_t)u0 * 128 + co);
    A0 = __hadd2(A0, u2h2(p0.x)); A1 = __hadd2(A1, u2h2(p0.y));
  }
  if (j < e && half == 0) {
    int u0 = edge_src[j];
    uint2 p0 = *reinterpret_cast<const uint2*>(hH + (size_t)u0 * 128 + co);
    A0 = __hadd2(A0, u2h2(p0.x)); A1 = __hadd2(A1, u2h2(p0.y));
  }
  float a0 = (__low2float(A0) + __low2float(B0)) + (__low2float(C0) + __low2float(D0));
  float a1 = (__high2float(A0) + __high2float(B0)) + (__high2float(C0) + __high2float(D0));
  float a2 = (__low2float(A1) + __low2float(B1)) + (__low2float(C1) + __low2float(D1));
  float a3 = (__high2float(A1) + __high2float(B1)) + (__high2float(C1) + __high2float(D1));
  a0 += __shfl_xor(a0, 32);
  a1 += __shfl_xor(a1, 32);
  a2 += __shfl_xor(a2, 32);
  a3 += __shfl_xor(a3, 32);
  if (half == 0) {
    const float niv = ni[v];
    uint2 po = {pk2h(a0 * niv, a1 * niv), pk2h(a2 * niv, a3 * niv)};
    *reinterpret_cast<uint2*>(aggH + (size_t)v * 128 + co) = po;
  }
}

// ====== final gather, 64-wide: out[v] = ni[v]*sum z[u] + b2  (f32 out) ====
__global__ __launch_bounds__(256) void gather_out(
    const unsigned short* __restrict__ zH, const int* __restrict__ row_start,
    const int* __restrict__ edge_src, const float* __restrict__ ni,
    const float* __restrict__ bias, float* __restrict__ out, int N) {
  const int v = blockIdx.x * 4 + (threadIdx.x >> 6);
  if (v >= N) return;
  const int l = threadIdx.x & 63;
  const int half = l >> 5;
  const int lane = l & 31;
  const int s = row_start[v];
  const int e = row_start[v + 1];
  const int co = 2 * lane;
  const __half2 z = __float2half2_rn(0.f);
  __half2 A = z, B = z, C = z, D = z;
  int j = s;
  for (; j + 8 <= e; j += 8) {
    int u0 = edge_src[j + half];
    int u1 = edge_src[j + 2 + half];
    int u2 = edge_src[j + 4 + half];
    int u3 = edge_src[j + 6 + half];
    A = __hadd2(A, u2h2(*reinterpret_cast<const unsigned int*>(zH + (size_t)u0 * 64 + co)));
    B = __hadd2(B, u2h2(*reinterpret_cast<const unsigned int*>(zH + (size_t)u1 * 64 + co)));
    C = __hadd2(C, u2h2(*reinterpret_cast<const unsigned int*>(zH + (size_t)u2 * 64 + co)));
    D = __hadd2(D, u2h2(*reinterpret_cast<const unsigned int*>(zH + (size_t)u3 * 64 + co)));
  }
  for (; j + 2 <= e; j += 2) {
    int u0 = edge_src[j + half];
    A = __hadd2(A, u2h2(*reinterpret_cast<const unsigned int*>(zH + (size_t)u0 * 64 + co)));
  }
  if (j < e && half == 0) {
    int u0 = edge_src[j];
    A = __hadd2(A, u2h2(*reinterpret_cast<const unsigned int*>(zH + (size_t)u0 * 64 + co)));
  }
  float a0 = (__low2float(A) + __low2float(B)) + (__low2float(C) + __low2float(D));
  float a1 = (__high2float(A) + __high2float(B)) + (__high2float(C) + __high2float(D));
  a0 += __shfl_xor(a0, 32);
  a1 += __shfl_xor(a1, 32);
  if (half == 0) {
    const float niv = ni[v];
    float2 bb = *reinterpret_cast<const float2*>(bias + co);
    float2 w = {a0 * niv + bb.x, a1 * niv + bb.y};
    *reinterpret_cast<float2*>(out + (size_t)v * 64 + co) = w;
  }
}

// ====== MFMA matmul [N,128]x[128,128] + bias + LN + ReLU + no-fold (f16) ==
__global__ __launch_bounds__(256) void mm_mfma_ln(
    const unsigned short* __restrict__ A, const unsigned short* __restrict__ Wt,
    const float* __restrict__ b, const float* __restrict__ g,
    const float* __restrict__ be, const float* __restrict__ no,
    unsigned short* __restrict__ out, int N) {
  __shared__ float sS[2][2][16];
  __shared__ float sQ[2][2][16];
  __shared__ float sNo[32];
  const int rbase = blockIdx.x * 32;
  const int w = threadIdx.x >> 6;
  const int l = threadIdx.x & 63;
  const int rt = w & 1, ch = w >> 1;
  if (threadIdx.x < 32) sNo[threadIdx.x] = no[min(rbase + (int)threadIdx.x, N - 1)];
  const int arow = min(rbase + rt * 16 + (l & 15), N - 1);
  const int kof = (l >> 4) * 8;

  f16x8 af[4];
  const unsigned short* ap = A + (size_t)arow * 128 + kof;
#pragma unroll
  for (int kk = 0; kk < 4; ++kk)
    af[kk] = *reinterpret_cast<const f16x8*>(ap + kk * 32);

  f32x4 acc[4] = {};
#pragma unroll
  for (int ct = 0; ct < 4; ++ct) {
    const int ccol = ch * 64 + ct * 16 + (l & 15);
    const unsigned short* bp = Wt + (size_t)ccol * 128 + kof;
#pragma unroll
    for (int kk = 0; kk < 4; ++kk) {
      f16x8 bfr = *reinterpret_cast<const f16x8*>(bp + kk * 32);
      acc[ct] = __builtin_amdgcn_mfma_f32_16x16x32_f16(af[kk], bfr, acc[ct], 0, 0, 0);
    }
  }

  float s[4] = {0.f, 0.f, 0.f, 0.f}, q[4] = {0.f, 0.f, 0.f, 0.f};
#pragma unroll
  for (int ct = 0; ct < 4; ++ct) {
    const float bc = b[ch * 64 + ct * 16 + (l & 15)];
#pragma unroll
    for (int j = 0; j < 4; ++j) {
      float v = acc[ct][j] + bc;
      acc[ct][j] = v;
      s[j] += v;
      q[j] += v * v;
    }
  }
#pragma unroll
  for (int j = 0; j < 4; ++j) {
#pragma unroll
    for (int off = 1; off < 16; off <<= 1) {
      s[j] += __shfl_xor(s[j], off);
      q[j] += __shfl_xor(q[j], off);
    }
  }
  const int grp = l >> 4;
  if ((l & 15) == 0) {
#pragma unroll
    for (int j = 0; j < 4; ++j) {
      sS[rt][ch][grp * 4 + j] = s[j];
      sQ[rt][ch][grp * 4 + j] = q[j];
    }
  }
  __syncthreads();

#pragma unroll
  for (int j = 0; j < 4; ++j) {
    const int r = grp * 4 + j;
    const int row = rbase + rt * 16 + r;
    float S = sS[rt][0][r] + sS[rt][1][r];
    float Q = sQ[rt][0][r] + sQ[rt][1][r];
    float mu = S * (1.f / 128.f);
    float rstd = rsqrtf(fmaxf(Q * (1.f / 128.f) - mu * mu, 0.f) + LN_EPS);
    float nof = sNo[rt * 16 + r];
    if (row < N) {
#pragma unroll
      for (int ct = 0; ct < 4; ++ct) {
        const int ccol = ch * 64 + ct * 16 + (l & 15);
        float y = (acc[ct][j] - mu) * rstd * g[ccol] + be[ccol];
        y = fmaxf(y, 0.f) * nof;
        out[(size_t)row * 128 + ccol] = f2h(y);
      }
    }
  }
}

// ====== z = h @ W2 -> f16 [N,64], NO bias (commuted final layer) ==========
__global__ __launch_bounds__(256) void mm_z_mfma(
    const unsigned short* __restrict__ A, const unsigned short* __restrict__ Wt,
    unsigned short* __restrict__ zH, int N) {
  const int rbase = blockIdx.x * 32;
  const int w = threadIdx.x >> 6;
  const int l = threadIdx.x & 63;
  const int rt = w & 1, ch = w >> 1;
  const int arow = min(rbase + rt * 16 + (l & 15), N - 1);
  const int kof = (l >> 4) * 8;

  f16x8 af[4];
  const unsigned short* ap = A + (size_t)arow * 128 + kof;
#pragma unroll
  for (int kk = 0; kk < 4; ++kk)
    af[kk] = *reinterpret_cast<const f16x8*>(ap + kk * 32);

  f32x4 acc[2] = {};
#pragma unroll
  for (int ct = 0; ct < 2; ++ct) {
    const int ccol = ch * 32 + ct * 16 + (l & 15);
    const unsigned short* bp = Wt + (size_t)ccol * 128 + kof;
#pragma unroll
    for (int kk = 0; kk < 4; ++kk) {
      f16x8 bfr = *reinterpret_cast<const f16x8*>(bp + kk * 32);
      acc[ct] = __builtin_amdgcn_mfma_f32_16x16x32_f16(af[kk], bfr, acc[ct], 0, 0, 0);
    }
  }
  const int grp = l >> 4;
#pragma unroll
  for (int ct = 0; ct < 2; ++ct) {
    const int ccol = ch * 32 + ct * 16 + (l & 15);
#pragma unroll
    for (int j = 0; j < 4; ++j) {
      const int row = rbase + rt * 16 + grp * 4 + j;
      if (row < N) zH[(size_t)row * 64 + ccol] = f2h(acc[ct][j]);
    }
  }
}

extern "C" void kernel_launch(void* const* d_in, const int* in_sizes, int n_in,
                              void* d_out, int out_size, void* d_ws, size_t ws_size,
                              hipStream_t stream) {
  const float* feats = (const float*)d_in[0];
  const int*   src   = (const int*)d_in[1];
  const int*   dst   = (const int*)d_in[2];
  const float* W0    = (const float*)d_in[3];
  const float* b0    = (const float*)d_in[4];
  const float* g0    = (const float*)d_in[5];
  const float* be0   = (const float*)d_in[6];
  const float* W1    = (const float*)d_in[7];
  const float* b1    = (const float*)d_in[8];
  const float* g1    = (const float*)d_in[9];
  const float* be1   = (const float*)d_in[10];
  const float* W2    = (const float*)d_in[11];
  const float* b2    = (const float*)d_in[12];
  float* out = (float*)d_out;

  const int n = in_sizes[0] / 128;  // 100000
  const int e = in_sizes[1];        // 1600000
  const int NB = (n + NPB - 1) / NPB;        // 391 buckets
  const int NBLK = (e + CHUNK - 1) / CHUNK;  // 391 chunks

  float* ws = (float*)d_ws;
  auto pad4 = [](size_t x) { return (x + 3) & ~(size_t)3; };
  size_t o = 0;
  float* norm_o  = ws + o; o = pad4(o + n);
  float* norm_i  = ws + o; o = pad4(o + n);
  int*   cntD    = (int*)(ws + o); o = pad4(o + (size_t)NB * NBLK);
  int*   cntS    = (int*)(ws + o); o = pad4(o + (size_t)NB * NBLK);
  int*   offLD   = (int*)(ws + o); o = pad4(o + (size_t)NB * NBLK);
  int*   offLS   = (int*)(ws + o); o = pad4(o + (size_t)NB * NBLK);
  int*   totD    = (int*)(ws + o); o = pad4(o + NB);
  int*   totS    = (int*)(ws + o); o = pad4(o + NB);
  int*   bkt_stD = (int*)(ws + o); o = pad4(o + NB + 1);
  int*   bkt_stS = (int*)(ws + o); o = pad4(o + NB + 1);
  int*   row_st  = (int*)(ws + o); o = pad4(o + n + 1);
  unsigned int*  packedD = (unsigned int*)(ws + o);  o = pad4(o + (size_t)e);
  unsigned char* srcS    = (unsigned char*)(ws + o); o = pad4(o + (size_t)(e + 3) / 4);
  int*   edg_src = (int*)(ws + o); o = pad4(o + (size_t)e);
  unsigned short* featH = (unsigned short*)(ws + o); o = pad4(o + (size_t)n * 64);  // also hH
  unsigned short* aggH  = (unsigned short*)(ws + o); o = pad4(o + (size_t)n * 64);  // also zH
  unsigned short* Wt0   = (unsigned short*)(ws + o); o = pad4(o + 128 * 128 / 2);
  unsigned short* Wt1   = (unsigned short*)(ws + o); o = pad4(o + 128 * 128 / 2);
  unsigned short* Wt2   = (unsigned short*)(ws + o); o = pad4(o + 128 * 64 / 2);
  unsigned short* hH = featH;  // featH dead after layer-0 gather
  unsigned short* zH = aggH;   // aggH dead after layer-1 mm

  // ---- CSR build: atomic-free radix partition ----
  passA_kernel<<<NBLK, 256, 2 * NB * sizeof(int), stream>>>(src, dst, cntD, cntS, NB, NBLK, e);
  scan1_kernel<<<2 * NB, 512, 0, stream>>>(cntD, cntS, offLD, offLS, totD, totS, NB, NBLK);
  scan2_kernel<<<1, 512, 0, stream>>>(totD, totS, bkt_stD, bkt_stS, row_st, NB, n, e);
  passB_kernel<<<NBLK, 256, 0, stream>>>(src, dst, cntD, cntS, offLD, offLS, bkt_stD, bkt_stS,
                                         packedD, srcS, NB, NBLK, e);
  passC_kernel<<<NB, 256, 0, stream>>>(packedD, bkt_stD, row_st, norm_i, edg_src, n);
  passD_kernel<<<NB, 256, 0, stream>>>(srcS, bkt_stS, norm_o, n);

  // ---- weights -> f16 transposed; feats -> f16 with no-fold ----
  wconv_kernel<<<(128 * 128 + 255) / 256, 256, 0, stream>>>(W0, Wt0, 128, 128);
  wconv_kernel<<<(128 * 128 + 255) / 256, 256, 0, stream>>>(W1, Wt1, 128, 128);
  wconv_kernel<<<(128 * 64 + 255) / 256, 256, 0, stream>>>(W2, Wt2, 128, 64);
  featconv_kernel<<<(n + 7) / 8, 256, 0, stream>>>(feats, norm_o, featH, n);

  const int gblocks = (n + 3) / 4;
  const int mblocks = (n + 31) / 32;

  // layer 0
  gather_agg_h<<<gblocks, 256, 0, stream>>>(featH, row_st, edg_src, norm_i, aggH, n);
  mm_mfma_ln<<<mblocks, 256, 0, stream>>>(aggH, Wt0, b0, g0, be0, norm_o, hH, n);
  // layer 1
  gather_agg_h<<<gblocks, 256, 0, stream>>>(hH, row_st, edg_src, norm_i, aggH, n);
  mm_mfma_ln<<<mblocks, 256, 0, stream>>>(aggH, Wt1, b1, g1, be1, norm_o, hH, n);
  // final layer (commuted): z = hH@W2, then 64-wide gather + bias -> out
  mm_z_mfma<<<mblocks, 256, 0, stream>>>(hH, Wt2, zH, n);
  gather_out<<<gblocks, 256, 0, stream>>>(zH, row_st, edg_src, norm_i, b2, out, n);
}